// Round 10
// baseline (319.802 us; speedup 1.0000x reference)
//
#include <hip/hip_runtime.h>
#include <hip/hip_bf16.h>

using bf16 = __hip_bfloat16;
typedef __attribute__((ext_vector_type(8))) short short8;
typedef __attribute__((ext_vector_type(4))) float f32x4;

#define DM 2048
#define DL 512
#define NH 16
#define DKH 128
#define BB 2
#define SS 2048
#define MTOT (BB*SS)

__device__ __forceinline__ short f2b(float f) {
  bf16 h = __float2bfloat16(f);
  return *reinterpret_cast<short*>(&h);
}

__device__ __forceinline__ unsigned cvt_pk_bf16(float lo, float hi) {
  unsigned r;
  asm("v_cvt_pk_bf16_f32 %0, %1, %2" : "=v"(r) : "v"(lo), "v"(hi));
  return r;
}

__device__ __forceinline__ void gll16(const void* g, void* l) {
  __builtin_amdgcn_global_load_lds(
      (const __attribute__((address_space(1))) void*)g,
      (__attribute__((address_space(3))) void*)l, 16, 0, 0);
}

// ---------------- fp32 -> bf16 elementwise ----------------
__global__ void cvt_kernel(const float* __restrict__ in, bf16* __restrict__ out, int n) {
  int idx = (blockIdx.x * blockDim.x + threadIdx.x) * 4;
  int stride = gridDim.x * blockDim.x * 4;
  short* o = reinterpret_cast<short*>(out);
  for (int i = idx; i < n; i += stride) {
    float4 v = *reinterpret_cast<const float4*>(in + i);
    short4 s;
    s.x = f2b(v.x); s.y = f2b(v.y); s.z = f2b(v.z); s.w = f2b(v.w);
    *reinterpret_cast<short4*>(o + i) = s;
  }
}

// ---------------- weight transpose + convert: w (K x N f32) -> wt (N x K bf16) ----------------
__global__ __launch_bounds__(256) void wtrans_kernel(const float* __restrict__ w,
                                                     bf16* __restrict__ wt, int K, int N) {
  __shared__ float tile[64][65];
  int tn = blockIdx.x, tk = blockIdx.y;
  int t = threadIdx.x;
  int c = t & 63, r4 = t >> 6;
  const float* src = w + (size_t)(tk * 64) * N + tn * 64;
  #pragma unroll
  for (int rr = 0; rr < 64; rr += 4)
    tile[rr + r4][c] = src[(size_t)(rr + r4) * N + c];
  __syncthreads();
  bf16* dst = wt + (size_t)(tn * 64) * K + tk * 64;
  #pragma unroll
  for (int rr = 0; rr < 64; rr += 4)
    dst[(size_t)(rr + r4) * K + c] = __float2bfloat16(tile[c][rr + r4]);
}

// ---------------- GEMM v2-8w: 2-phase pipelined, BK=64, double-buffered, swizzled LDS ----
template<int EPI>
__global__ __launch_bounds__(512, 4) void gemm_bt2(const bf16* __restrict__ A, const bf16* __restrict__ BT,
                                                   const float* __restrict__ bias, void* __restrict__ Cout,
                                                   int N, int K, float oscale) {
  __shared__ __align__(16) char smem[65536];
  int nbn = N >> 7;
  int nwg = gridDim.x;
  int bid = blockIdx.x;
  int cpx = nwg >> 3;
  bid = (bid & 7) * cpx + (bid >> 3);       // XCD-aware swizzle
  int m0 = (bid / nbn) << 7;
  int n0 = (bid % nbn) << 7;
  int t = threadIdx.x, lane = t & 63, wid = t >> 6;
  int wr = (wid >> 2) << 6;
  int wc = (wid & 3) << 5;
  int l15 = lane & 15, l4 = lane >> 4;

  const char* asrc[2]; const char* bsrc[2]; int ldso[2];
  #pragma unroll
  for (int j = 0; j < 2; ++j) {
    int cbase = (wid * 2 + j) * 64;
    int chunk = cbase + lane;
    int off = chunk << 4;
    int row = off >> 7, col = off & 127;
    int scol = col ^ ((row & 7) << 4);
    asrc[j] = (const char*)(A + (size_t)(m0 + row) * K) + scol;
    bsrc[j] = (const char*)(BT + (size_t)(n0 + row) * K) + scol;
    ldso[j] = cbase << 4;
  }

  #pragma unroll
  for (int j = 0; j < 2; ++j) {
    gll16(asrc[j], smem + ldso[j]);
    gll16(bsrc[j], smem + 32768 + ldso[j]);
    asrc[j] += 128;
    bsrc[j] += 128;
  }
  __syncthreads();

  f32x4 acc[4][2];
  #pragma unroll
  for (int i = 0; i < 4; ++i)
    #pragma unroll
    for (int j = 0; j < 2; ++j) acc[i][j] = (f32x4){0.f, 0.f, 0.f, 0.f};

  int cur = 0;
  for (int kt = 0; kt < K; kt += 64) {
    if (kt + 64 < K) {
      char* an = smem + ((cur ^ 1) << 14);
      char* bn = smem + 32768 + ((cur ^ 1) << 14);
      #pragma unroll
      for (int j = 0; j < 2; ++j) {
        gll16(asrc[j], an + ldso[j]);
        gll16(bsrc[j], bn + ldso[j]);
      }
    }
    #pragma unroll
    for (int j = 0; j < 2; ++j) { asrc[j] += 128; bsrc[j] += 128; }

    const char* ab = smem + (cur << 14);
    const char* bb = smem + 32768 + (cur << 14);
    short8 af[4][2], bfr[2][2];
    #pragma unroll
    for (int ks = 0; ks < 2; ++ks) {
      #pragma unroll
      for (int i = 0; i < 4; ++i) {
        int row = wr + i * 16 + l15;
        int bo = row * 128 + ((ks * 64 + (l4 << 4)) ^ ((row & 7) << 4));
        af[i][ks] = *reinterpret_cast<const short8*>(ab + bo);
      }
      #pragma unroll
      for (int j2 = 0; j2 < 2; ++j2) {
        int row = wc + j2 * 16 + l15;
        int bo = row * 128 + ((ks * 64 + (l4 << 4)) ^ ((row & 7) << 4));
        bfr[j2][ks] = *reinterpret_cast<const short8*>(bb + bo);
      }
    }
    #pragma unroll
    for (int ks = 0; ks < 2; ++ks)
      #pragma unroll
      for (int i = 0; i < 4; ++i)
        #pragma unroll
        for (int j2 = 0; j2 < 2; ++j2)
          acc[i][j2] = __builtin_amdgcn_mfma_f32_16x16x32_bf16(af[i][ks], bfr[j2][ks], acc[i][j2], 0, 0, 0);

    __syncthreads();
    cur ^= 1;
  }

  int r0 = m0 + wr + (l4 << 2);
  int c0 = n0 + wc + l15;
  #pragma unroll
  for (int i = 0; i < 4; ++i) {
    #pragma unroll
    for (int j = 0; j < 2; ++j) {
      int col = c0 + j * 16;
      float bs = bias[col];
      #pragma unroll
      for (int g = 0; g < 4; ++g) {
        int row = r0 + i * 16 + g;
        float v = (acc[i][j][g] + bs) * oscale;
        if (EPI == 0) {
          ((bf16*)Cout)[(size_t)row * N + col] = __float2bfloat16(v);
        } else if (EPI == 1) {
          ((float*)Cout)[(size_t)row * N + col] = v;
        } else {
          int b = row >> 11, s = row & (SS - 1);
          int h = col >> 7, dd = col & (DKH - 1);
          ((bf16*)Cout)[((size_t)((b * NH + h) * DKH + dd)) * SS + s] = __float2bfloat16(v);
        }
      }
    }
  }
}

// ---------------- flash attention v2: m=4 per wave, intra-block KV-split ----------------
// 4 waves: wave w -> kv-half h=w>>1, q-rows (w&1)*64..+63 (m=4 groups of 16).
// KVBLK=32, per-half double-buffered K/V (K 4x8K + V 4x8K + pScr 4x4K = 80KB).
// kf/vf fragments amortized over 4 m-groups -> LDS reads/MFMA halved vs m=2.
// Partial (O,m,l) of the two halves merged through LDS in the epilogue.
__global__ __launch_bounds__(256, 2) void mla_attn(const bf16* __restrict__ q, const bf16* __restrict__ k,
                                                   const bf16* __restrict__ vT, bf16* __restrict__ ctx) {
  __shared__ __align__(16) char smem[81920];

  // ---- XCD-locality swizzle (grid = 512, 8 XCDs, 32 bh * 16 qt) ----
  int bid = blockIdx.x;
  int x = bid & 7;
  int r = bid >> 3;
  int l = (r < 32) ? (2 * r) : (2 * (r - 32) + 1);
  int lbid = x * 64 + l;
  int bh = lbid >> 4, qt = lbid & 15;
  int b = bh >> 4, hh = bh & 15;

  int t = threadIdx.x, lane = t & 63, w = t >> 6;
  int l15 = lane & 15, l4 = lane >> 4;
  int h = w >> 1, wq = w & 1;

  const bf16* qbase = q + ((size_t)(b * SS + qt * 128)) * DM + hh * DKH;
  const bf16* kbase = k + ((size_t)(b * SS + h * 1024)) * DM + hh * DKH;   // this wave's kv-half
  const bf16* vbase = vT + ((size_t)(bh * DKH)) * SS + h * 1024;

  char* pScr = smem + 65536 + (w << 12);           // wave-private 4KB P
  char* sKeven = smem + 32768 + (h << 14);         // even tiles: K here, V at +8K
  char* sKodd  = smem + (h << 14);                 // odd tiles (overwrites Q region)

  // ---- prologue: Q -> smem[0,32K) rows 0..127 x 256B swizzled; tile0 K/V -> V-space ----
  #pragma unroll
  for (int j = 0; j < 8; ++j) {
    int grp = w * 8 + j;
    int chunk = grp * 64 + lane;
    int off = chunk << 4;
    int rr = off >> 8;
    int cb = (off & 255) ^ ((rr & 7) << 4);
    gll16((const char*)qbase + (size_t)rr * DM * 2 + cb, smem + (grp << 10));
  }
  {
    int th = w >> 1, isV = w & 1;   // w0:K0h0 w1:V0h0 w2:K0h1 w3:V0h1
    const char* kb2 = (const char*)(k + ((size_t)(b * SS + th * 1024)) * DM + hh * DKH);
    const char* vb2 = (const char*)(vT + ((size_t)(bh * DKH)) * SS + th * 1024);
    char* dst0 = smem + 32768 + (th << 14) + (isV ? 8192 : 0);
    #pragma unroll
    for (int j = 0; j < 8; ++j) {
      int chunk = j * 64 + lane;
      int off = chunk << 4;
      if (!isV) {
        int rr = off >> 8;                       // kv row 0..31
        int cb = (off & 255) ^ ((rr & 7) << 4);
        gll16(kb2 + (size_t)rr * DM * 2 + cb, dst0 + (j << 10));
      } else {
        int line = chunk >> 3, s8 = chunk & 7;
        int lg = s8 ^ (line & 7);
        int hi = lg >> 2, c16 = lg & 3;
        int d = line + (hi << 6);
        gll16(vb2 + (size_t)d * SS * 2 + (c16 << 4), dst0 + (j << 10));
      }
    }
  }
  __syncthreads();   // Q + tile0 landed (each wave drains own vmcnt before barrier)

  // q fragments: this wave's 64 q-rows (B-operand for swapped QK^T)
  short8 qf[4][4];
  #pragma unroll
  for (int m = 0; m < 4; ++m)
    #pragma unroll
    for (int ks = 0; ks < 4; ++ks) {
      int row = wq * 64 + m * 16 + l15;
      int kb = (ks * 64 + (l4 << 4)) ^ ((row & 7) << 4);
      qf[m][ks] = *reinterpret_cast<const short8*>(smem + row * 256 + kb);
    }
  __syncthreads();   // all qf reads done before iter0 prefetch overwrites Q region

  // staging pointers for in-loop prefetch (tile 1 onward); 32-bit lane offsets + running base
  unsigned koff[4], voff[4];
  int ldk[4];
  #pragma unroll
  for (int j = 0; j < 4; ++j) {
    int ck = (wq * 4 + j) * 64 + lane;
    int offk = ck << 4;
    int kr = offk >> 8;
    koff[j] = (unsigned)(32 + kr) * (DM * 2) + ((offk & 255) ^ ((kr & 7) << 4));
    int line = ck >> 3, s8 = ck & 7;
    int lg = s8 ^ (line & 7);
    int hi = lg >> 2, c16 = lg & 3;
    int d = line + (hi << 6);
    voff[j] = (unsigned)d * (SS * 2) + 64 + (c16 << 4);
    ldk[j] = (wq * 4 + j) << 10;
  }
  unsigned krun = 0, vrun = 0;

  f32x4 po[4][8];
  #pragma unroll
  for (int m = 0; m < 4; ++m)
    #pragma unroll
    for (int n = 0; n < 8; ++n) po[m][n] = (f32x4){0.f, 0.f, 0.f, 0.f};
  float mrun[4] = {-1e30f, -1e30f, -1e30f, -1e30f};
  float lrun[4] = {0.f, 0.f, 0.f, 0.f};

  for (int tt = 0; tt < 32; ++tt) {
    char* kcur = (tt & 1) ? sKodd : sKeven;
    char* vcur = kcur + 8192;

    // prefetch tile tt+1 into the opposite-parity slots (stays in flight through compute)
    if (tt < 31) {
      char* knxt = (tt & 1) ? sKeven : sKodd;
      char* vnxt = knxt + 8192;
      #pragma unroll
      for (int j = 0; j < 4; ++j) {
        gll16((const char*)kbase + (size_t)(koff[j] + krun), knxt + ldk[j]);
        gll16((const char*)vbase + (size_t)(voff[j] + vrun), vnxt + ldk[j]);
      }
    }
    krun += 32 * DM * 2;
    vrun += 64;

    // ---- S^T = K Q^T : ps[m][n] = P^T[kv=16n+4*l4+g][q = wq*64+m*16+l15] ----
    f32x4 ps[4][2];
    #pragma unroll
    for (int m = 0; m < 4; ++m)
      #pragma unroll
      for (int n = 0; n < 2; ++n) ps[m][n] = (f32x4){0.f, 0.f, 0.f, 0.f};
    __builtin_amdgcn_s_setprio(1);
    #pragma unroll
    for (int ks = 0; ks < 4; ++ks) {
      #pragma unroll
      for (int n = 0; n < 2; ++n) {
        int row = n * 16 + l15;
        int kb = (ks * 64 + (l4 << 4)) ^ ((row & 7) << 4);
        short8 kf = *reinterpret_cast<const short8*>(kcur + row * 256 + kb);
        #pragma unroll
        for (int m = 0; m < 4; ++m)
          ps[m][n] = __builtin_amdgcn_mfma_f32_16x16x32_bf16(kf, qf[m][ks], ps[m][n], 0, 0, 0);
      }
    }
    __builtin_amdgcn_s_setprio(0);

    // ---- online softmax (log2 domain; per-q state lane-local at l15) ----
    float tmax[4];
    bool grow = false;
    #pragma unroll
    for (int m = 0; m < 4; ++m) {
      f32x4 vm = ps[m][0];
      #pragma unroll
      for (int g = 0; g < 4; ++g) vm[g] = fmaxf(vm[g], ps[m][1][g]);
      float v = fmaxf(fmaxf(vm[0], vm[1]), fmaxf(vm[2], vm[3]));
      v = fmaxf(v, __shfl_xor(v, 16));
      v = fmaxf(v, __shfl_xor(v, 32));
      tmax[m] = v;
      grow |= (v > mrun[m] + 11.5415603f);   // 8*log2(e)
    }
    if (__any(grow)) {
      #pragma unroll
      for (int m = 0; m < 4; ++m) {
        float mnew = fmaxf(mrun[m], tmax[m]);
        float a = __builtin_amdgcn_exp2f(mrun[m] - mnew);
        mrun[m] = mnew;
        lrun[m] *= a;
        float aO[4];
        #pragma unroll
        for (int g = 0; g < 4; ++g) aO[g] = __shfl(a, (l4 << 2) + g);
        #pragma unroll
        for (int n = 0; n < 8; ++n)
          #pragma unroll
          for (int g = 0; g < 4; ++g) po[m][n][g] *= aO[g];
      }
    }

    // ---- exp + b64 P-writes (line-packed pScr: line lq = [q | q+32], 8 slots) ----
    #pragma unroll
    for (int m = 0; m < 4; ++m) {
      int lq = ((m & 1) << 4) + l15;
      float mr = mrun[m];
      float rs = 0.f;
      #pragma unroll
      for (int n = 0; n < 2; ++n) {
        float p0 = __builtin_amdgcn_exp2f(ps[m][n][0] - mr);
        float p1 = __builtin_amdgcn_exp2f(ps[m][n][1] - mr);
        float p2 = __builtin_amdgcn_exp2f(ps[m][n][2] - mr);
        float p3 = __builtin_amdgcn_exp2f(ps[m][n][3] - mr);
        rs += (p0 + p1) + (p2 + p3);
        int phys = (((m >> 1) << 2) + 2 * n + (l4 >> 1)) ^ (l15 & 7);
        *reinterpret_cast<uint2*>(pScr + lq * 128 + phys * 16 + ((l4 & 1) << 3)) =
            make_uint2(cvt_pk_bf16(p0, p1), cvt_pk_bf16(p2, p3));
      }
      rs += __shfl_xor(rs, 16);
      rs += __shfl_xor(rs, 32);
      lrun[m] += rs;
    }

    // ---- O += P V  (pa: 1/m; vf: 8 shared across all m) ----
    __builtin_amdgcn_s_setprio(1);
    short8 pa[4];
    #pragma unroll
    for (int m = 0; m < 4; ++m) {
      int lq = ((m & 1) << 4) + l15;
      int phys = ((((m >> 1) << 2) + l4) ^ (l15 & 7));
      pa[m] = *reinterpret_cast<const short8*>(pScr + lq * 128 + phys * 16);
    }
    #pragma unroll
    for (int n = 0; n < 8; ++n) {
      int d = 16 * n + l15;
      int line = d & 63;
      int phys = ((((n >> 2) << 2) + l4) ^ (l15 & 7));
      short8 vf = *reinterpret_cast<const short8*>(vcur + line * 128 + phys * 16);
      #pragma unroll
      for (int m = 0; m < 4; ++m)
        po[m][n] = __builtin_amdgcn_mfma_f32_16x16x32_bf16(pa[m], vf, po[m][n], 0, 0, 0);
    }
    __builtin_amdgcn_s_setprio(0);

    __syncthreads();   // drains own vmcnt(0): prefetch landed; all waves' reads done
  }

  // ---- epilogue: merge the two kv-halves (wave w<2 with partner w+2), store ctx ----
  if (w >= 2) {
    float* reg = (float*)(smem + ((w - 2) << 15));
    #pragma unroll
    for (int m = 0; m < 4; ++m)
      #pragma unroll
      for (int n = 0; n < 8; ++n)
        #pragma unroll
        for (int g = 0; g < 4; ++g)
          reg[(m * 16 + (l4 << 2) + g) * 128 + n * 16 + l15] = po[m][n][g];
    float* pml = (float*)(smem + 65536 + ((w - 2) << 10));
    #pragma unroll
    for (int m = 0; m < 4; ++m) {
      pml[((m << 4) + l15) * 2] = mrun[m];
      pml[((m << 4) + l15) * 2 + 1] = lrun[m];
    }
  }
  __syncthreads();
  if (w < 2) {
    float* reg = (float*)(smem + (w << 15));
    float* pml = (float*)(smem + 65536 + (w << 10));
    #pragma unroll
    for (int m = 0; m < 4; ++m) {
      float mB = pml[((m << 4) + l15) * 2];
      float lB = pml[((m << 4) + l15) * 2 + 1];
      float mf = fmaxf(mrun[m], mB);
      float aA = __builtin_amdgcn_exp2f(mrun[m] - mf);
      float aB = __builtin_amdgcn_exp2f(mB - mf);
      float linv = 1.f / (lrun[m] * aA + lB * aB);
      float aAO[4], aBO[4], ivO[4];
      #pragma unroll
      for (int g = 0; g < 4; ++g) {
        int src = (l4 << 2) + g;
        aAO[g] = __shfl(aA, src);
        aBO[g] = __shfl(aB, src);
        ivO[g] = __shfl(linv, src);
      }
      #pragma unroll
      for (int g = 0; g < 4; ++g) {
        int qrow = qt * 128 + w * 64 + m * 16 + (l4 << 2) + g;
        bf16* dst = ctx + ((size_t)(b * SS + qrow)) * DM + hh * DKH;
        #pragma unroll
        for (int n = 0; n < 8; ++n) {
          float ob = reg[(m * 16 + (l4 << 2) + g) * 128 + n * 16 + l15];
          dst[n * 16 + l15] = __float2bfloat16((po[m][n][g] * aAO[g] + ob * aBO[g]) * ivO[g]);
        }
      }
    }
  }
}

extern "C" void kernel_launch(void* const* d_in, const int* in_sizes, int n_in,
                              void* d_out, int out_size, void* d_ws, size_t ws_size,
                              hipStream_t stream) {
  (void)in_sizes; (void)n_in; (void)out_size; (void)ws_size;
  const float* x     = (const float*)d_in[0];
  const float* wq    = (const float*)d_in[2];
  const float* wqb   = (const float*)d_in[3];
  const float* wkvd  = (const float*)d_in[4];
  const float* wkvdb = (const float*)d_in[5];
  const float* wku   = (const float*)d_in[6];
  const float* wkub  = (const float*)d_in[7];
  const float* wvu   = (const float*)d_in[8];
  const float* wvub  = (const float*)d_in[9];
  const float* wo    = (const float*)d_in[10];
  const float* wob   = (const float*)d_in[11];

  char* ws = (char*)d_ws;
  size_t off = 0;
  auto alloc = [&](size_t nbytes) { void* p = ws + off; off += (nbytes + 255) & ~(size_t)255; return p; };
  bf16* xb    = (bf16*)alloc((size_t)MTOT * DM * 2);
  bf16* wqT   = (bf16*)alloc((size_t)DM * DM * 2);
  bf16* wkvdT = (bf16*)alloc((size_t)DL * DM * 2);
  bf16* wkuT  = (bf16*)alloc((size_t)DM * DL * 2);
  bf16* wvuT  = (bf16*)alloc((size_t)DM * DL * 2);
  bf16* woT   = (bf16*)alloc((size_t)DM * DM * 2);
  bf16* qb    = (bf16*)alloc((size_t)MTOT * DM * 2);
  bf16* kvl   = (bf16*)alloc((size_t)MTOT * DL * 2);
  bf16* kb    = (bf16*)alloc((size_t)MTOT * DM * 2);
  bf16* vTb   = (bf16*)alloc((size_t)MTOT * DM * 2);
  bf16* ctxb  = (bf16*)alloc((size_t)MTOT * DM * 2);

  // 1/sqrt(128) * log2(e): scores land in log2 domain for native v_exp_f32 softmax
  const float qscale = 0.08838834764831845f * 1.4426950408889634f;

  cvt_kernel<<<2048, 256, 0, stream>>>(x, xb, MTOT * DM);
  wtrans_kernel<<<dim3(DM / 64, DM / 64), 256, 0, stream>>>(wq,   wqT,   DM, DM);
  wtrans_kernel<<<dim3(DL / 64, DM / 64), 256, 0, stream>>>(wkvd, wkvdT, DM, DL);
  wtrans_kernel<<<dim3(DM / 64, DL / 64), 256, 0, stream>>>(wku,  wkuT,  DL, DM);
  wtrans_kernel<<<dim3(DM / 64, DL / 64), 256, 0, stream>>>(wvu,  wvuT,  DL, DM);
  wtrans_kernel<<<dim3(DM / 64, DM / 64), 256, 0, stream>>>(wo,   woT,   DM, DM);

  gemm_bt2<0><<<(MTOT / 128) * (DM / 128), 512, 0, stream>>>(xb,  wqT,   wqb,   qb,  DM, DM, qscale);
  gemm_bt2<0><<<(MTOT / 128) * (DL / 128), 512, 0, stream>>>(xb,  wkvdT, wkvdb, kvl, DL, DM, 1.f);
  gemm_bt2<0><<<(MTOT / 128) * (DM / 128), 512, 0, stream>>>(kvl, wkuT,  wkub,  kb,  DM, DL, 1.f);
  gemm_bt2<2><<<(MTOT / 128) * (DM / 128), 512, 0, stream>>>(kvl, wvuT,  wvub,  vTb, DM, DL, 1.f);
  mla_attn<<<BB * NH * (SS / 128), 256, 0, stream>>>(qb, kb, vTb, ctxb);
  gemm_bt2<1><<<(MTOT / 128) * (DM / 128), 512, 0, stream>>>(ctxb, woT, wob, d_out, DM, DM, 1.f);
}

// Round 11
// 250.787 us; speedup vs baseline: 1.2752x; 1.2752x over previous
//
#include <hip/hip_runtime.h>
#include <hip/hip_bf16.h>

using bf16 = __hip_bfloat16;
typedef __attribute__((ext_vector_type(8))) short short8;
typedef __attribute__((ext_vector_type(4))) float f32x4;

#define DM 2048
#define DL 512
#define NH 16
#define DKH 128
#define BB 2
#define SS 2048
#define MTOT (BB*SS)

__device__ __forceinline__ short f2b(float f) {
  bf16 h = __float2bfloat16(f);
  return *reinterpret_cast<short*>(&h);
}

__device__ __forceinline__ unsigned cvt_pk_bf16(float lo, float hi) {
  unsigned r;
  asm("v_cvt_pk_bf16_f32 %0, %1, %2" : "=v"(r) : "v"(lo), "v"(hi));
  return r;
}

__device__ __forceinline__ void gll16(const void* g, void* l) {
  __builtin_amdgcn_global_load_lds(
      (const __attribute__((address_space(1))) void*)g,
      (__attribute__((address_space(3))) void*)l, 16, 0, 0);
}

// ---------------- fp32 -> bf16 elementwise ----------------
__global__ void cvt_kernel(const float* __restrict__ in, bf16* __restrict__ out, int n) {
  int idx = (blockIdx.x * blockDim.x + threadIdx.x) * 4;
  int stride = gridDim.x * blockDim.x * 4;
  short* o = reinterpret_cast<short*>(out);
  for (int i = idx; i < n; i += stride) {
    float4 v = *reinterpret_cast<const float4*>(in + i);
    short4 s;
    s.x = f2b(v.x); s.y = f2b(v.y); s.z = f2b(v.z); s.w = f2b(v.w);
    *reinterpret_cast<short4*>(o + i) = s;
  }
}

// ---------------- weight transpose + convert: w (K x N f32) -> wt (N x K bf16) ----------------
__global__ __launch_bounds__(256) void wtrans_kernel(const float* __restrict__ w,
                                                     bf16* __restrict__ wt, int K, int N) {
  __shared__ float tile[64][65];
  int tn = blockIdx.x, tk = blockIdx.y;
  int t = threadIdx.x;
  int c = t & 63, r4 = t >> 6;
  const float* src = w + (size_t)(tk * 64) * N + tn * 64;
  #pragma unroll
  for (int rr = 0; rr < 64; rr += 4)
    tile[rr + r4][c] = src[(size_t)(rr + r4) * N + c];
  __syncthreads();
  bf16* dst = wt + (size_t)(tn * 64) * K + tk * 64;
  #pragma unroll
  for (int rr = 0; rr < 64; rr += 4)
    dst[(size_t)(rr + r4) * K + c] = __float2bfloat16(tile[c][rr + r4]);
}

// ---------------- dual-job GEMM: 2-phase pipelined, BK=64, double-buffered, swizzled LDS ----
// Two GEMM jobs (same A-matrix-kind layout & same K) packed into one grid: blocks
// [0,nblkA) run job A (BTa/biasa/Couta/Na/osa, epilogue EPIA); the rest run job B.
// Inner loop is the proven round-7 2-phase structure, verbatim.
// EPI 0: bf16 row-major. EPI 1: f32 row-major. EPI 2: bf16 as V^T (B*NH, DKH, SS).
template<int EPIA, int EPIB>
__global__ __launch_bounds__(256, 2) void gemm_dual(const bf16* __restrict__ A,
                                                    const bf16* __restrict__ BTa, const float* __restrict__ biasa,
                                                    void* __restrict__ Couta, int Na, float osa,
                                                    const bf16* __restrict__ BTb, const float* __restrict__ biasb,
                                                    void* __restrict__ Coutb, int Nb, float osb,
                                                    int K, int nblkA) {
  __shared__ __align__(16) char smem[65536];
  int nwg = gridDim.x;
  int bid = blockIdx.x;
  int cpx = nwg >> 3;                       // all grids %8==0
  bid = (bid & 7) * cpx + (bid >> 3);       // XCD-aware swizzle
  bool jobB = (bid >= nblkA);
  const bf16* BT = jobB ? BTb : BTa;
  const float* bias = jobB ? biasb : biasa;
  void* Cout = jobB ? Coutb : Couta;
  int N = jobB ? Nb : Na;
  float oscale = jobB ? osb : osa;
  int lb = jobB ? (bid - nblkA) : bid;
  int epi = jobB ? EPIB : EPIA;
  int nbn = N >> 7;
  int m0 = (lb / nbn) << 7;
  int n0 = (lb % nbn) << 7;
  int t = threadIdx.x, lane = t & 63, wid = t >> 6;
  int wr = (wid >> 1) << 6, wc = (wid & 1) << 6;
  int l15 = lane & 15, l4 = lane >> 4;

  const char* asrc[4]; const char* bsrc[4]; int ldso[4];
  #pragma unroll
  for (int j = 0; j < 4; ++j) {
    int cbase = (wid * 4 + j) * 64;
    int chunk = cbase + lane;
    int off = chunk << 4;
    int row = off >> 7, col = off & 127;
    int scol = col ^ ((row & 7) << 4);
    asrc[j] = (const char*)(A + (size_t)(m0 + row) * K) + scol;
    bsrc[j] = (const char*)(BT + (size_t)(n0 + row) * K) + scol;
    ldso[j] = cbase << 4;
  }

  #pragma unroll
  for (int j = 0; j < 4; ++j) {
    gll16(asrc[j], smem + ldso[j]);
    gll16(bsrc[j], smem + 32768 + ldso[j]);
    asrc[j] += 128;
    bsrc[j] += 128;
  }
  __syncthreads();

  f32x4 acc[4][4];
  #pragma unroll
  for (int i = 0; i < 4; ++i)
    #pragma unroll
    for (int j = 0; j < 4; ++j) acc[i][j] = (f32x4){0.f, 0.f, 0.f, 0.f};

  int cur = 0;
  for (int kt = 0; kt < K; kt += 64) {
    if (kt + 64 < K) {
      char* an = smem + ((cur ^ 1) << 14);
      char* bn = smem + 32768 + ((cur ^ 1) << 14);
      #pragma unroll
      for (int j = 0; j < 4; ++j) {
        gll16(asrc[j], an + ldso[j]);
        gll16(bsrc[j], bn + ldso[j]);
      }
    }
    #pragma unroll
    for (int j = 0; j < 4; ++j) { asrc[j] += 128; bsrc[j] += 128; }

    const char* ab = smem + (cur << 14);
    const char* bb = smem + 32768 + (cur << 14);
    short8 af[4][2], bfr[4][2];
    #pragma unroll
    for (int ks = 0; ks < 2; ++ks) {
      #pragma unroll
      for (int i = 0; i < 4; ++i) {
        int row = wr + i * 16 + l15;
        int bo = row * 128 + ((ks * 64 + (l4 << 4)) ^ ((row & 7) << 4));
        af[i][ks] = *reinterpret_cast<const short8*>(ab + bo);
      }
      #pragma unroll
      for (int j2 = 0; j2 < 4; ++j2) {
        int row = wc + j2 * 16 + l15;
        int bo = row * 128 + ((ks * 64 + (l4 << 4)) ^ ((row & 7) << 4));
        bfr[j2][ks] = *reinterpret_cast<const short8*>(bb + bo);
      }
    }
    #pragma unroll
    for (int ks = 0; ks < 2; ++ks)
      #pragma unroll
      for (int i = 0; i < 4; ++i)
        #pragma unroll
        for (int j2 = 0; j2 < 4; ++j2)
          acc[i][j2] = __builtin_amdgcn_mfma_f32_16x16x32_bf16(af[i][ks], bfr[j2][ks], acc[i][j2], 0, 0, 0);

    __syncthreads();
    cur ^= 1;
  }

  int r0 = m0 + wr + (l4 << 2);
  int c0 = n0 + wc + l15;
  #pragma unroll
  for (int i = 0; i < 4; ++i) {
    #pragma unroll
    for (int j = 0; j < 4; ++j) {
      int col = c0 + j * 16;
      float bs = bias[col];
      #pragma unroll
      for (int g = 0; g < 4; ++g) {
        int row = r0 + i * 16 + g;
        float v = (acc[i][j][g] + bs) * oscale;
        if (epi == 0) {
          ((bf16*)Cout)[(size_t)row * N + col] = __float2bfloat16(v);
        } else if (epi == 1) {
          ((float*)Cout)[(size_t)row * N + col] = v;
        } else {
          int b = row >> 11, s = row & (SS - 1);
          int h = col >> 7, dd = col & (DKH - 1);
          ((bf16*)Cout)[((size_t)((b * NH + h) * DKH + dd)) * SS + s] = __float2bfloat16(v);
        }
      }
    }
  }
}

// ---------------- single-job GEMM (round-7 structure) for the output projection ----------
template<int EPI>
__global__ __launch_bounds__(256, 2) void gemm_bt2(const bf16* __restrict__ A, const bf16* __restrict__ BT,
                                                   const float* __restrict__ bias, void* __restrict__ Cout,
                                                   int N, int K, float oscale) {
  __shared__ __align__(16) char smem[65536];
  int nbn = N >> 7;
  int nwg = gridDim.x;
  int bid = blockIdx.x;
  int cpx = nwg >> 3;
  bid = (bid & 7) * cpx + (bid >> 3);
  int m0 = (bid / nbn) << 7;
  int n0 = (bid % nbn) << 7;
  int t = threadIdx.x, lane = t & 63, wid = t >> 6;
  int wr = (wid >> 1) << 6, wc = (wid & 1) << 6;
  int l15 = lane & 15, l4 = lane >> 4;

  const char* asrc[4]; const char* bsrc[4]; int ldso[4];
  #pragma unroll
  for (int j = 0; j < 4; ++j) {
    int cbase = (wid * 4 + j) * 64;
    int chunk = cbase + lane;
    int off = chunk << 4;
    int row = off >> 7, col = off & 127;
    int scol = col ^ ((row & 7) << 4);
    asrc[j] = (const char*)(A + (size_t)(m0 + row) * K) + scol;
    bsrc[j] = (const char*)(BT + (size_t)(n0 + row) * K) + scol;
    ldso[j] = cbase << 4;
  }

  #pragma unroll
  for (int j = 0; j < 4; ++j) {
    gll16(asrc[j], smem + ldso[j]);
    gll16(bsrc[j], smem + 32768 + ldso[j]);
    asrc[j] += 128;
    bsrc[j] += 128;
  }
  __syncthreads();

  f32x4 acc[4][4];
  #pragma unroll
  for (int i = 0; i < 4; ++i)
    #pragma unroll
    for (int j = 0; j < 4; ++j) acc[i][j] = (f32x4){0.f, 0.f, 0.f, 0.f};

  int cur = 0;
  for (int kt = 0; kt < K; kt += 64) {
    if (kt + 64 < K) {
      char* an = smem + ((cur ^ 1) << 14);
      char* bn = smem + 32768 + ((cur ^ 1) << 14);
      #pragma unroll
      for (int j = 0; j < 4; ++j) {
        gll16(asrc[j], an + ldso[j]);
        gll16(bsrc[j], bn + ldso[j]);
      }
    }
    #pragma unroll
    for (int j = 0; j < 4; ++j) { asrc[j] += 128; bsrc[j] += 128; }

    const char* ab = smem + (cur << 14);
    const char* bb = smem + 32768 + (cur << 14);
    short8 af[4][2], bfr[4][2];
    #pragma unroll
    for (int ks = 0; ks < 2; ++ks) {
      #pragma unroll
      for (int i = 0; i < 4; ++i) {
        int row = wr + i * 16 + l15;
        int bo = row * 128 + ((ks * 64 + (l4 << 4)) ^ ((row & 7) << 4));
        af[i][ks] = *reinterpret_cast<const short8*>(ab + bo);
      }
      #pragma unroll
      for (int j2 = 0; j2 < 4; ++j2) {
        int row = wc + j2 * 16 + l15;
        int bo = row * 128 + ((ks * 64 + (l4 << 4)) ^ ((row & 7) << 4));
        bfr[j2][ks] = *reinterpret_cast<const short8*>(bb + bo);
      }
    }
    #pragma unroll
    for (int ks = 0; ks < 2; ++ks)
      #pragma unroll
      for (int i = 0; i < 4; ++i)
        #pragma unroll
        for (int j2 = 0; j2 < 4; ++j2)
          acc[i][j2] = __builtin_amdgcn_mfma_f32_16x16x32_bf16(af[i][ks], bfr[j2][ks], acc[i][j2], 0, 0, 0);

    __syncthreads();
    cur ^= 1;
  }

  int r0 = m0 + wr + (l4 << 2);
  int c0 = n0 + wc + l15;
  #pragma unroll
  for (int i = 0; i < 4; ++i) {
    #pragma unroll
    for (int j = 0; j < 4; ++j) {
      int col = c0 + j * 16;
      float bs = bias[col];
      #pragma unroll
      for (int g = 0; g < 4; ++g) {
        int row = r0 + i * 16 + g;
        float v = (acc[i][j][g] + bs) * oscale;
        if (EPI == 0) {
          ((bf16*)Cout)[(size_t)row * N + col] = __float2bfloat16(v);
        } else if (EPI == 1) {
          ((float*)Cout)[(size_t)row * N + col] = v;
        } else {
          int b = row >> 11, s = row & (SS - 1);
          int h = col >> 7, dd = col & (DKH - 1);
          ((bf16*)Cout)[((size_t)((b * NH + h) * DKH + dd)) * SS + s] = __float2bfloat16(v);
        }
      }
    }
  }
}

// ---------------- flash attention, 2-phase pipelined, KVBLK=64, swapped QK^T ----------------
// (round-7 kernel, verbatim -- proven 100us / MfmaUtil 29%)
__global__ __launch_bounds__(256, 2) void mla_attn(const bf16* __restrict__ q, const bf16* __restrict__ k,
                                                   const bf16* __restrict__ vT, bf16* __restrict__ ctx) {
  __shared__ __align__(16) char smemB[81920];

  int bid = blockIdx.x;
  int x = bid & 7;
  int r = bid >> 3;
  int l = (r < 32) ? (2 * r) : (2 * (r - 32) + 1);
  int lbid = x * 64 + l;
  int bh = lbid >> 4, qt = lbid & 15;
  int b = bh >> 4, h = bh & 15;

  int t = threadIdx.x, lane = t & 63, wid = t >> 6;
  int l15 = lane & 15, l4 = lane >> 4;
  char* pScr = smemB + 65536 + (wid << 12);   // wave-private 4KB: [32 q][64 k] bf16, swizzled

  const bf16* qbase = q + ((size_t)(b * SS + qt * 128)) * DM + h * DKH;
  const bf16* kbase = k + ((size_t)(b * SS)) * DM + h * DKH;
  const bf16* vbase = vT + ((size_t)(bh * DKH)) * SS;

  #pragma unroll
  for (int j = 0; j < 8; ++j) {
    int grp = wid * 8 + j;
    int chunk = grp * 64 + lane;
    int off = chunk << 4;
    int rr = off >> 8;
    int cb = (off & 255) ^ ((rr & 7) << 4);
    char* dst = smemB + ((grp < 16) ? (grp << 10) : (32768 + ((grp - 16) << 10)));
    gll16((const char*)(qbase + (size_t)rr * DM) + cb, dst);
  }
  const char* kap[4]; const char* vap[4]; int ldsoA[4];
  #pragma unroll
  for (int j = 0; j < 4; ++j) {
    int cbase = (wid * 4 + j) * 64;
    int chunk = cbase + lane;
    int off = chunk << 4;
    int kr = off >> 8;
    int kcb = (off & 255) ^ ((kr & 7) << 4);
    gll16((const char*)(kbase + (size_t)kr * DM) + kcb, smemB + 16384 + (cbase << 4));
    int vr = off >> 7;
    int vcb = (off & 127) ^ ((vr & 7) << 4);
    gll16((const char*)(vbase + (size_t)vr * SS) + vcb, smemB + 49152 + (cbase << 4));
    kap[j] = (const char*)(kbase + (size_t)(64 + kr) * DM) + kcb;
    vap[j] = (const char*)(vbase + (size_t)vr * SS + 64) + vcb;
    ldsoA[j] = cbase << 4;
  }
  asm volatile("s_waitcnt vmcnt(8)" ::: "memory");
  __builtin_amdgcn_s_barrier();
  __builtin_amdgcn_sched_barrier(0);

  short8 qf[2][4];
  #pragma unroll
  for (int m = 0; m < 2; ++m)
    #pragma unroll
    for (int ks = 0; ks < 4; ++ks) {
      int row = wid * 32 + m * 16 + l15;
      const char* qsrc = smemB + ((row < 64) ? (row * 256) : (32768 + (row - 64) * 256));
      int kb = (ks * 64 + (l4 << 4)) ^ ((row & 7) << 4);
      qf[m][ks] = *reinterpret_cast<const short8*>(qsrc + kb);
    }

  f32x4 po[2][8];
  #pragma unroll
  for (int m = 0; m < 2; ++m)
    #pragma unroll
    for (int n = 0; n < 8; ++n) po[m][n] = (f32x4){0.f, 0.f, 0.f, 0.f};
  float mrun[2] = {-1e30f, -1e30f};
  float lrun[2] = {0.f, 0.f};

  int cur = 1;
  __syncthreads();

  for (int tt = 0; tt < 32; ++tt) {
    char* kcur = smemB + (cur << 14);
    char* vcur = smemB + 32768 + (cur << 14);

    if (tt + 1 < 32) {
      char* knxt = smemB + ((cur ^ 1) << 14);
      char* vnxt = smemB + 32768 + ((cur ^ 1) << 14);
      #pragma unroll
      for (int j = 0; j < 4; ++j) {
        gll16(kap[j], knxt + ldsoA[j]);
        gll16(vap[j], vnxt + ldsoA[j]);
      }
    }
    #pragma unroll
    for (int j = 0; j < 4; ++j) { kap[j] += 64 * DM * 2; vap[j] += 128; }

    f32x4 ps[2][4];
    #pragma unroll
    for (int m = 0; m < 2; ++m)
      #pragma unroll
      for (int n = 0; n < 4; ++n) ps[m][n] = (f32x4){0.f, 0.f, 0.f, 0.f};
    __builtin_amdgcn_s_setprio(1);
    #pragma unroll
    for (int ks = 0; ks < 4; ++ks) {
      #pragma unroll
      for (int n = 0; n < 4; ++n) {
        int row = n * 16 + l15;
        int kb = (ks * 64 + (l4 << 4)) ^ ((row & 7) << 4);
        short8 kf = *reinterpret_cast<const short8*>(kcur + row * 256 + kb);
        ps[0][n] = __builtin_amdgcn_mfma_f32_16x16x32_bf16(kf, qf[0][ks], ps[0][n], 0, 0, 0);
        ps[1][n] = __builtin_amdgcn_mfma_f32_16x16x32_bf16(kf, qf[1][ks], ps[1][n], 0, 0, 0);
      }
    }
    __builtin_amdgcn_s_setprio(0);

    float tmax[2];
    bool grow = false;
    #pragma unroll
    for (int m = 0; m < 2; ++m) {
      f32x4 vm = ps[m][0];
      #pragma unroll
      for (int n = 1; n < 4; ++n)
        #pragma unroll
        for (int g = 0; g < 4; ++g) vm[g] = fmaxf(vm[g], ps[m][n][g]);
      float v = fmaxf(fmaxf(vm[0], vm[1]), fmaxf(vm[2], vm[3]));
      v = fmaxf(v, __shfl_xor(v, 16));
      v = fmaxf(v, __shfl_xor(v, 32));
      tmax[m] = v;
      grow |= (v > mrun[m] + 11.5415603f);
    }
    if (__any(grow)) {
      float alpha[2];
      #pragma unroll
      for (int m = 0; m < 2; ++m) {
        float mnew = fmaxf(mrun[m], tmax[m]);
        alpha[m] = __builtin_amdgcn_exp2f(mrun[m] - mnew);
        mrun[m] = mnew;
        lrun[m] *= alpha[m];
      }
      #pragma unroll
      for (int m = 0; m < 2; ++m) {
        float aO[4];
        #pragma unroll
        for (int g = 0; g < 4; ++g) aO[g] = __shfl(alpha[m], (l4 << 2) + g);
        #pragma unroll
        for (int n = 0; n < 8; ++n)
          #pragma unroll
          for (int g = 0; g < 4; ++g) po[m][n][g] *= aO[g];
      }
    }

    #pragma unroll
    for (int m = 0; m < 2; ++m) {
      int qrow = m * 16 + l15;
      int swz = (qrow & 7) << 4;
      char* base = pScr + qrow * 128;
      float mr = mrun[m];
      float sn[4];
      #pragma unroll
      for (int n = 0; n < 4; ++n) {
        float p0 = __builtin_amdgcn_exp2f(ps[m][n][0] - mr);
        float p1 = __builtin_amdgcn_exp2f(ps[m][n][1] - mr);
        float p2 = __builtin_amdgcn_exp2f(ps[m][n][2] - mr);
        float p3 = __builtin_amdgcn_exp2f(ps[m][n][3] - mr);
        *reinterpret_cast<unsigned*>(base + ((n * 32 + l4 * 8 + 0) ^ swz)) = cvt_pk_bf16(p0, p1);
        *reinterpret_cast<unsigned*>(base + ((n * 32 + l4 * 8 + 4) ^ swz)) = cvt_pk_bf16(p2, p3);
        sn[n] = (p0 + p1) + (p2 + p3);
      }
      float rs = (sn[0] + sn[1]) + (sn[2] + sn[3]);
      rs += __shfl_xor(rs, 16);
      rs += __shfl_xor(rs, 32);
      lrun[m] += rs;

      __builtin_amdgcn_s_setprio(1);
      #pragma unroll
      for (int ks = 0; ks < 2; ++ks) {
        short8 pa = *reinterpret_cast<const short8*>(
            base + ((ks * 64 + (l4 << 4)) ^ swz));
        #pragma unroll
        for (int n = 0; n < 8; ++n) {
          int vrow = n * 16 + l15;
          int vb = (ks * 64 + (l4 << 4)) ^ ((vrow & 7) << 4);
          short8 vf = *reinterpret_cast<const short8*>(vcur + vrow * 128 + vb);
          po[m][n] = __builtin_amdgcn_mfma_f32_16x16x32_bf16(pa, vf, po[m][n], 0, 0, 0);
        }
      }
      __builtin_amdgcn_s_setprio(0);
    }

    __syncthreads();
    cur ^= 1;
  }

  #pragma unroll
  for (int m = 0; m < 2; ++m) {
    float invO[4];
    #pragma unroll
    for (int g = 0; g < 4; ++g) invO[g] = 1.f / __shfl(lrun[m], (l4 << 2) + g);
    #pragma unroll
    for (int g = 0; g < 4; ++g) {
      int qrow = qt * 128 + wid * 32 + m * 16 + (l4 << 2) + g;
      bf16* dst = ctx + ((size_t)(b * SS + qrow)) * DM + h * DKH;
      #pragma unroll
      for (int n = 0; n < 8; ++n)
        dst[n * 16 + l15] = __float2bfloat16(po[m][n][g] * invO[g]);
    }
  }
}

extern "C" void kernel_launch(void* const* d_in, const int* in_sizes, int n_in,
                              void* d_out, int out_size, void* d_ws, size_t ws_size,
                              hipStream_t stream) {
  (void)in_sizes; (void)n_in; (void)out_size; (void)ws_size;
  const float* x     = (const float*)d_in[0];
  const float* wq    = (const float*)d_in[2];
  const float* wqb   = (const float*)d_in[3];
  const float* wkvd  = (const float*)d_in[4];
  const float* wkvdb = (const float*)d_in[5];
  const float* wku   = (const float*)d_in[6];
  const float* wkub  = (const float*)d_in[7];
  const float* wvu   = (const float*)d_in[8];
  const float* wvub  = (const float*)d_in[9];
  const float* wo    = (const float*)d_in[10];
  const float* wob   = (const float*)d_in[11];

  char* ws = (char*)d_ws;
  size_t off = 0;
  auto alloc = [&](size_t nbytes) { void* p = ws + off; off += (nbytes + 255) & ~(size_t)255; return p; };
  bf16* xb    = (bf16*)alloc((size_t)MTOT * DM * 2);
  bf16* wqT   = (bf16*)alloc((size_t)DM * DM * 2);
  bf16* wkvdT = (bf16*)alloc((size_t)DL * DM * 2);
  bf16* wkuT  = (bf16*)alloc((size_t)DM * DL * 2);
  bf16* wvuT  = (bf16*)alloc((size_t)DM * DL * 2);
  bf16* woT   = (bf16*)alloc((size_t)DM * DM * 2);
  bf16* qb    = (bf16*)alloc((size_t)MTOT * DM * 2);
  bf16* kvl   = (bf16*)alloc((size_t)MTOT * DL * 2);
  bf16* kb    = (bf16*)alloc((size_t)MTOT * DM * 2);
  bf16* vTb   = (bf16*)alloc((size_t)MTOT * DM * 2);
  bf16* ctxb  = (bf16*)alloc((size_t)MTOT * DM * 2);

  // 1/sqrt(128) * log2(e): scores land in log2 domain for native v_exp_f32 softmax
  const float qscale = 0.08838834764831845f * 1.4426950408889634f;

  cvt_kernel<<<2048, 256, 0, stream>>>(x, xb, MTOT * DM);
  wtrans_kernel<<<dim3(DM / 64, DM / 64), 256, 0, stream>>>(wq,   wqT,   DM, DM);
  wtrans_kernel<<<dim3(DL / 64, DM / 64), 256, 0, stream>>>(wkvd, wkvdT, DM, DL);
  wtrans_kernel<<<dim3(DM / 64, DL / 64), 256, 0, stream>>>(wku,  wkuT,  DL, DM);
  wtrans_kernel<<<dim3(DM / 64, DL / 64), 256, 0, stream>>>(wvu,  wvuT,  DL, DM);
  wtrans_kernel<<<dim3(DM / 64, DM / 64), 256, 0, stream>>>(wo,   woT,   DM, DM);

  // q (512 blocks) + kv-down (128 blocks) fused: kvd fills the chip alongside q
  gemm_dual<0, 0><<<(MTOT / 128) * (DM / 128) + (MTOT / 128) * (DL / 128), 256, 0, stream>>>(
      xb, wqT, wqb, qb, DM, qscale,
      wkvdT, wkvdb, kvl, DL, 1.f,
      DM, (MTOT / 128) * (DM / 128));
  // k-up (EPI0) + v-up (EPI2, writes V^T) fused
  gemm_dual<0, 2><<<2 * (MTOT / 128) * (DM / 128), 256, 0, stream>>>(
      kvl, wkuT, wkub, kb, DM, 1.f,
      wvuT, wvub, vTb, DM, 1.f,
      DL, (MTOT / 128) * (DM / 128));
  mla_attn<<<BB * NH * (SS / 128), 256, 0, stream>>>(qb, kb, vTb, ctxb);
  gemm_bt2<1><<<(MTOT / 128) * (DM / 128), 256, 0, stream>>>(ctxb, woT, wob, d_out, DM, DM, 1.f);
}

// Round 12
// 242.115 us; speedup vs baseline: 1.3209x; 1.0358x over previous
//
#include <hip/hip_runtime.h>
#include <hip/hip_bf16.h>

using bf16 = __hip_bfloat16;
typedef __attribute__((ext_vector_type(8))) short short8;
typedef __attribute__((ext_vector_type(4))) float f32x4;

#define DM 2048
#define DL 512
#define NH 16
#define DKH 128
#define BB 2
#define SS 2048
#define MTOT (BB*SS)

__device__ __forceinline__ short f2b(float f) {
  bf16 h = __float2bfloat16(f);
  return *reinterpret_cast<short*>(&h);
}

__device__ __forceinline__ unsigned cvt_pk_bf16(float lo, float hi) {
  unsigned r;
  asm("v_cvt_pk_bf16_f32 %0, %1, %2" : "=v"(r) : "v"(lo), "v"(hi));
  return r;
}

__device__ __forceinline__ void gll16(const void* g, void* l) {
  __builtin_amdgcn_global_load_lds(
      (const __attribute__((address_space(1))) void*)g,
      (__attribute__((address_space(3))) void*)l, 16, 0, 0);
}

// ---------------- fp32 -> bf16 elementwise ----------------
__global__ void cvt_kernel(const float* __restrict__ in, bf16* __restrict__ out, int n) {
  int idx = (blockIdx.x * blockDim.x + threadIdx.x) * 4;
  int stride = gridDim.x * blockDim.x * 4;
  short* o = reinterpret_cast<short*>(out);
  for (int i = idx; i < n; i += stride) {
    float4 v = *reinterpret_cast<const float4*>(in + i);
    short4 s;
    s.x = f2b(v.x); s.y = f2b(v.y); s.z = f2b(v.z); s.w = f2b(v.w);
    *reinterpret_cast<short4*>(o + i) = s;
  }
}

// ---------------- weight transpose + convert: w (K x N f32) -> wt (N x K bf16) ----------------
__global__ __launch_bounds__(256) void wtrans_kernel(const float* __restrict__ w,
                                                     bf16* __restrict__ wt, int K, int N) {
  __shared__ float tile[64][65];
  int tn = blockIdx.x, tk = blockIdx.y;
  int t = threadIdx.x;
  int c = t & 63, r4 = t >> 6;
  const float* src = w + (size_t)(tk * 64) * N + tn * 64;
  #pragma unroll
  for (int rr = 0; rr < 64; rr += 4)
    tile[rr + r4][c] = src[(size_t)(rr + r4) * N + c];
  __syncthreads();
  bf16* dst = wt + (size_t)(tn * 64) * K + tk * 64;
  #pragma unroll
  for (int rr = 0; rr < 64; rr += 4)
    dst[(size_t)(rr + r4) * K + c] = __float2bfloat16(tile[c][rr + r4]);
}

// ---------------- GEMM v2 (round-7, proven): 2-phase pipelined, BK=64, dbuf, swizzled ----
template<int EPI>
__global__ __launch_bounds__(256, 2) void gemm_bt2(const bf16* __restrict__ A, const bf16* __restrict__ BT,
                                                   const float* __restrict__ bias, void* __restrict__ Cout,
                                                   int N, int K, float oscale) {
  __shared__ __align__(16) char smem[65536];
  int nbn = N >> 7;
  int nwg = gridDim.x;
  int bid = blockIdx.x;
  int cpx = nwg >> 3;                       // all grids %8==0
  bid = (bid & 7) * cpx + (bid >> 3);       // XCD-aware swizzle
  int m0 = (bid / nbn) << 7;
  int n0 = (bid % nbn) << 7;
  int t = threadIdx.x, lane = t & 63, wid = t >> 6;
  int wr = (wid >> 1) << 6, wc = (wid & 1) << 6;
  int l15 = lane & 15, l4 = lane >> 4;

  const char* asrc[4]; const char* bsrc[4]; int ldso[4];
  #pragma unroll
  for (int j = 0; j < 4; ++j) {
    int cbase = (wid * 4 + j) * 64;
    int chunk = cbase + lane;
    int off = chunk << 4;
    int row = off >> 7, col = off & 127;
    int scol = col ^ ((row & 7) << 4);
    asrc[j] = (const char*)(A + (size_t)(m0 + row) * K) + scol;
    bsrc[j] = (const char*)(BT + (size_t)(n0 + row) * K) + scol;
    ldso[j] = cbase << 4;
  }

  #pragma unroll
  for (int j = 0; j < 4; ++j) {
    gll16(asrc[j], smem + ldso[j]);
    gll16(bsrc[j], smem + 32768 + ldso[j]);
    asrc[j] += 128;
    bsrc[j] += 128;
  }
  __syncthreads();

  f32x4 acc[4][4];
  #pragma unroll
  for (int i = 0; i < 4; ++i)
    #pragma unroll
    for (int j = 0; j < 4; ++j) acc[i][j] = (f32x4){0.f, 0.f, 0.f, 0.f};

  int cur = 0;
  for (int kt = 0; kt < K; kt += 64) {
    if (kt + 64 < K) {
      char* an = smem + ((cur ^ 1) << 14);
      char* bn = smem + 32768 + ((cur ^ 1) << 14);
      #pragma unroll
      for (int j = 0; j < 4; ++j) {
        gll16(asrc[j], an + ldso[j]);
        gll16(bsrc[j], bn + ldso[j]);
      }
    }
    #pragma unroll
    for (int j = 0; j < 4; ++j) { asrc[j] += 128; bsrc[j] += 128; }

    const char* ab = smem + (cur << 14);
    const char* bb = smem + 32768 + (cur << 14);
    short8 af[4][2], bfr[4][2];
    #pragma unroll
    for (int ks = 0; ks < 2; ++ks) {
      #pragma unroll
      for (int i = 0; i < 4; ++i) {
        int row = wr + i * 16 + l15;
        int bo = row * 128 + ((ks * 64 + (l4 << 4)) ^ ((row & 7) << 4));
        af[i][ks] = *reinterpret_cast<const short8*>(ab + bo);
      }
      #pragma unroll
      for (int j2 = 0; j2 < 4; ++j2) {
        int row = wc + j2 * 16 + l15;
        int bo = row * 128 + ((ks * 64 + (l4 << 4)) ^ ((row & 7) << 4));
        bfr[j2][ks] = *reinterpret_cast<const short8*>(bb + bo);
      }
    }
    #pragma unroll
    for (int ks = 0; ks < 2; ++ks)
      #pragma unroll
      for (int i = 0; i < 4; ++i)
        #pragma unroll
        for (int j2 = 0; j2 < 4; ++j2)
          acc[i][j2] = __builtin_amdgcn_mfma_f32_16x16x32_bf16(af[i][ks], bfr[j2][ks], acc[i][j2], 0, 0, 0);

    __syncthreads();
    cur ^= 1;
  }

  int r0 = m0 + wr + (l4 << 2);
  int c0 = n0 + wc + l15;
  #pragma unroll
  for (int i = 0; i < 4; ++i) {
    #pragma unroll
    for (int j = 0; j < 4; ++j) {
      int col = c0 + j * 16;
      float bs = bias[col];
      #pragma unroll
      for (int g = 0; g < 4; ++g) {
        int row = r0 + i * 16 + g;
        float v = (acc[i][j][g] + bs) * oscale;
        if (EPI == 0) {
          ((bf16*)Cout)[(size_t)row * N + col] = __float2bfloat16(v);
        } else if (EPI == 1) {
          ((float*)Cout)[(size_t)row * N + col] = v;
        } else {
          int b = row >> 11, s = row & (SS - 1);
          int h = col >> 7, dd = col & (DKH - 1);
          ((bf16*)Cout)[((size_t)((b * NH + h) * DKH + dd)) * SS + s] = __float2bfloat16(v);
        }
      }
    }
  }
}

// ---------------- flash attention: round-7 body + counted-vmcnt split barriers (T4) ----------
// Per tile: QK^T(t) [K ready] -> issue K(t+1),V(t+1) -> max/rescale -> vmcnt(8)+barrier
// [V(t) visible; t+1's 8 loads stay in flight] -> per-m {exp,P,PV} -> vmcnt(4)+barrier
// [K(t+1) visible; V(t+1) in flight].  vmcnt never drains to 0 inside the loop.
__global__ __launch_bounds__(256, 2) void mla_attn(const bf16* __restrict__ q, const bf16* __restrict__ k,
                                                   const bf16* __restrict__ vT, bf16* __restrict__ ctx) {
  __shared__ __align__(16) char smemB[81920];

  int bid = blockIdx.x;
  int x = bid & 7;
  int r = bid >> 3;
  int l = (r < 32) ? (2 * r) : (2 * (r - 32) + 1);
  int lbid = x * 64 + l;
  int bh = lbid >> 4, qt = lbid & 15;
  int b = bh >> 4, h = bh & 15;

  int t = threadIdx.x, lane = t & 63, wid = t >> 6;
  int l15 = lane & 15, l4 = lane >> 4;
  char* pScr = smemB + 65536 + (wid << 12);   // wave-private 4KB: [32 q][64 k] bf16, swizzled

  const bf16* qbase = q + ((size_t)(b * SS + qt * 128)) * DM + h * DKH;
  const bf16* kbase = k + ((size_t)(b * SS)) * DM + h * DKH;
  const bf16* vbase = vT + ((size_t)(bh * DKH)) * SS;

  // ---- prologue: Q -> [K0|V0] regions; tile0 K/V -> buf1 (K loads before V loads) ----
  #pragma unroll
  for (int j = 0; j < 8; ++j) {
    int grp = wid * 8 + j;
    int chunk = grp * 64 + lane;
    int off = chunk << 4;
    int rr = off >> 8;
    int cb = (off & 255) ^ ((rr & 7) << 4);
    char* dst = smemB + ((grp < 16) ? (grp << 10) : (32768 + ((grp - 16) << 10)));
    gll16((const char*)(qbase + (size_t)rr * DM) + cb, dst);
  }
  const char* kap[4]; const char* vap[4]; int ldsoA[4];
  #pragma unroll
  for (int j = 0; j < 4; ++j) {
    int cbase = (wid * 4 + j) * 64;
    int chunk = cbase + lane;
    int off = chunk << 4;
    int kr = off >> 8;
    int kcb = (off & 255) ^ ((kr & 7) << 4);
    gll16((const char*)(kbase + (size_t)kr * DM) + kcb, smemB + 16384 + (cbase << 4));
    kap[j] = (const char*)(kbase + (size_t)(64 + kr) * DM) + kcb;
    ldsoA[j] = cbase << 4;
  }
  #pragma unroll
  for (int j = 0; j < 4; ++j) {
    int cbase = (wid * 4 + j) * 64;
    int chunk = cbase + lane;
    int off = chunk << 4;
    int vr = off >> 7;
    int vcb = (off & 127) ^ ((vr & 7) << 4);
    gll16((const char*)(vbase + (size_t)vr * SS) + vcb, smemB + 49152 + (cbase << 4));
    vap[j] = (const char*)(vbase + (size_t)vr * SS + 64) + vcb;
  }
  asm volatile("s_waitcnt vmcnt(8)" ::: "memory");  // Q landed; K0/V0 (8) in flight
  __builtin_amdgcn_s_barrier();
  __builtin_amdgcn_sched_barrier(0);

  // q fragments (B-operand for swapped QK^T)
  short8 qf[2][4];
  #pragma unroll
  for (int m = 0; m < 2; ++m)
    #pragma unroll
    for (int ks = 0; ks < 4; ++ks) {
      int row = wid * 32 + m * 16 + l15;
      const char* qsrc = smemB + ((row < 64) ? (row * 256) : (32768 + (row - 64) * 256));
      int kb = (ks * 64 + (l4 << 4)) ^ ((row & 7) << 4);
      qf[m][ks] = *reinterpret_cast<const short8*>(qsrc + kb);
    }

  f32x4 po[2][8];
  #pragma unroll
  for (int m = 0; m < 2; ++m)
    #pragma unroll
    for (int n = 0; n < 8; ++n) po[m][n] = (f32x4){0.f, 0.f, 0.f, 0.f};
  float mrun[2] = {-1e30f, -1e30f};
  float lrun[2] = {0.f, 0.f};

  int cur = 1;
  // K(0) landed (V(0)'s 4 loads stay in flight); qf reads drained; all waves synced
  asm volatile("s_waitcnt vmcnt(4) lgkmcnt(0)" ::: "memory");
  __builtin_amdgcn_s_barrier();
  __builtin_amdgcn_sched_barrier(0);

  for (int tt = 0; tt < 32; ++tt) {
    char* kcur = smemB + (cur << 14);
    char* vcur = smemB + 32768 + (cur << 14);

    // ---- S^T = K Q^T (K(tt) ready; V(tt) may still be in flight) ----
    f32x4 ps[2][4];
    #pragma unroll
    for (int m = 0; m < 2; ++m)
      #pragma unroll
      for (int n = 0; n < 4; ++n) ps[m][n] = (f32x4){0.f, 0.f, 0.f, 0.f};
    __builtin_amdgcn_s_setprio(1);
    #pragma unroll
    for (int ks = 0; ks < 4; ++ks) {
      #pragma unroll
      for (int n = 0; n < 4; ++n) {
        int row = n * 16 + l15;
        int kb = (ks * 64 + (l4 << 4)) ^ ((row & 7) << 4);
        short8 kf = *reinterpret_cast<const short8*>(kcur + row * 256 + kb);
        ps[0][n] = __builtin_amdgcn_mfma_f32_16x16x32_bf16(kf, qf[0][ks], ps[0][n], 0, 0, 0);
        ps[1][n] = __builtin_amdgcn_mfma_f32_16x16x32_bf16(kf, qf[1][ks], ps[1][n], 0, 0, 0);
      }
    }
    __builtin_amdgcn_s_setprio(0);

    // ---- issue prefetch tt+1 (K first, then V) into the other buffers ----
    if (tt + 1 < 32) {
      char* knxt = smemB + ((cur ^ 1) << 14);
      char* vnxt = smemB + 32768 + ((cur ^ 1) << 14);
      #pragma unroll
      for (int j = 0; j < 4; ++j) gll16(kap[j], knxt + ldsoA[j]);
      #pragma unroll
      for (int j = 0; j < 4; ++j) gll16(vap[j], vnxt + ldsoA[j]);
    }
    #pragma unroll
    for (int j = 0; j < 4; ++j) { kap[j] += 64 * DM * 2; vap[j] += 128; }

    // ---- tile max / defer-max rescale (log2 domain) ----
    float tmax[2];
    bool grow = false;
    #pragma unroll
    for (int m = 0; m < 2; ++m) {
      f32x4 vm = ps[m][0];
      #pragma unroll
      for (int n = 1; n < 4; ++n)
        #pragma unroll
        for (int g = 0; g < 4; ++g) vm[g] = fmaxf(vm[g], ps[m][n][g]);
      float v = fmaxf(fmaxf(vm[0], vm[1]), fmaxf(vm[2], vm[3]));
      v = fmaxf(v, __shfl_xor(v, 16));
      v = fmaxf(v, __shfl_xor(v, 32));
      tmax[m] = v;
      grow |= (v > mrun[m] + 11.5415603f);   // 8*log2(e)
    }
    if (__any(grow)) {
      float alpha[2];
      #pragma unroll
      for (int m = 0; m < 2; ++m) {
        float mnew = fmaxf(mrun[m], tmax[m]);
        alpha[m] = __builtin_amdgcn_exp2f(mrun[m] - mnew);
        mrun[m] = mnew;
        lrun[m] *= alpha[m];
      }
      #pragma unroll
      for (int m = 0; m < 2; ++m) {
        float aO[4];
        #pragma unroll
        for (int g = 0; g < 4; ++g) aO[g] = __shfl(alpha[m], (l4 << 2) + g);
        #pragma unroll
        for (int n = 0; n < 8; ++n)
          #pragma unroll
          for (int g = 0; g < 4; ++g) po[m][n][g] *= aO[g];
      }
    }

    // ---- V(tt) visible to all waves; tt+1's 8 loads stay in flight ----
    if (tt + 1 < 32) asm volatile("s_waitcnt vmcnt(8) lgkmcnt(0)" ::: "memory");
    else             asm volatile("s_waitcnt vmcnt(0) lgkmcnt(0)" ::: "memory");
    __builtin_amdgcn_s_barrier();
    __builtin_amdgcn_sched_barrier(0);

    // ---- per m: exp + P-write + tree-sum, then that half's PV cluster ----
    #pragma unroll
    for (int m = 0; m < 2; ++m) {
      int qrow = m * 16 + l15;
      int swz = (qrow & 7) << 4;
      char* base = pScr + qrow * 128;
      float mr = mrun[m];
      float sn[4];
      #pragma unroll
      for (int n = 0; n < 4; ++n) {
        float p0 = __builtin_amdgcn_exp2f(ps[m][n][0] - mr);
        float p1 = __builtin_amdgcn_exp2f(ps[m][n][1] - mr);
        float p2 = __builtin_amdgcn_exp2f(ps[m][n][2] - mr);
        float p3 = __builtin_amdgcn_exp2f(ps[m][n][3] - mr);
        *reinterpret_cast<unsigned*>(base + ((n * 32 + l4 * 8 + 0) ^ swz)) = cvt_pk_bf16(p0, p1);
        *reinterpret_cast<unsigned*>(base + ((n * 32 + l4 * 8 + 4) ^ swz)) = cvt_pk_bf16(p2, p3);
        sn[n] = (p0 + p1) + (p2 + p3);
      }
      float rs = (sn[0] + sn[1]) + (sn[2] + sn[3]);
      rs += __shfl_xor(rs, 16);
      rs += __shfl_xor(rs, 32);
      lrun[m] += rs;

      __builtin_amdgcn_s_setprio(1);
      #pragma unroll
      for (int ks = 0; ks < 2; ++ks) {
        short8 pa = *reinterpret_cast<const short8*>(
            base + ((ks * 64 + (l4 << 4)) ^ swz));
        #pragma unroll
        for (int n = 0; n < 8; ++n) {
          int vrow = n * 16 + l15;
          int vb = (ks * 64 + (l4 << 4)) ^ ((vrow & 7) << 4);
          short8 vf = *reinterpret_cast<const short8*>(vcur + vrow * 128 + vb);
          po[m][n] = __builtin_amdgcn_mfma_f32_16x16x32_bf16(pa, vf, po[m][n], 0, 0, 0);
        }
      }
      __builtin_amdgcn_s_setprio(0);
    }

    // ---- K(tt+1) visible before next QK; V(tt+1) stays in flight ----
    if (tt + 1 < 32) {
      asm volatile("s_waitcnt vmcnt(4) lgkmcnt(0)" ::: "memory");
      __builtin_amdgcn_s_barrier();
      __builtin_amdgcn_sched_barrier(0);
    }
    cur ^= 1;
  }

  // ---- epilogue: ctx = O / l ----
  #pragma unroll
  for (int m = 0; m < 2; ++m) {
    float invO[4];
    #pragma unroll
    for (int g = 0; g < 4; ++g) invO[g] = 1.f / __shfl(lrun[m], (l4 << 2) + g);
    #pragma unroll
    for (int g = 0; g < 4; ++g) {
      int qrow = qt * 128 + wid * 32 + m * 16 + (l4 << 2) + g;
      bf16* dst = ctx + ((size_t)(b * SS + qrow)) * DM + h * DKH;
      #pragma unroll
      for (int n = 0; n < 8; ++n)
        dst[n * 16 + l15] = __float2bfloat16(po[m][n][g] * invO[g]);
    }
  }
}

extern "C" void kernel_launch(void* const* d_in, const int* in_sizes, int n_in,
                              void* d_out, int out_size, void* d_ws, size_t ws_size,
                              hipStream_t stream) {
  (void)in_sizes; (void)n_in; (void)out_size; (void)ws_size;
  const float* x     = (const float*)d_in[0];
  const float* wq    = (const float*)d_in[2];
  const float* wqb   = (const float*)d_in[3];
  const float* wkvd  = (const float*)d_in[4];
  const float* wkvdb = (const float*)d_in[5];
  const float* wku   = (const float*)d_in[6];
  const float* wkub  = (const float*)d_in[7];
  const float* wvu   = (const float*)d_in[8];
  const float* wvub  = (const float*)d_in[9];
  const float* wo    = (const float*)d_in[10];
  const float* wob   = (const float*)d_in[11];

  char* ws = (char*)d_ws;
  size_t off = 0;
  auto alloc = [&](size_t nbytes) { void* p = ws + off; off += (nbytes + 255) & ~(size_t)255; return p; };
  bf16* xb    = (bf16*)alloc((size_t)MTOT * DM * 2);
  bf16* wqT   = (bf16*)alloc((size_t)DM * DM * 2);
  bf16* wkvdT = (bf16*)alloc((size_t)DL * DM * 2);
  bf16* wkuT  = (bf16*)alloc((size_t)DM * DL * 2);
  bf16* wvuT  = (bf16*)alloc((size_t)DM * DL * 2);
  bf16* woT   = (bf16*)alloc((size_t)DM * DM * 2);
  bf16* qb    = (bf16*)alloc((size_t)MTOT * DM * 2);
  bf16* kvl   = (bf16*)alloc((size_t)MTOT * DL * 2);
  bf16* kb    = (bf16*)alloc((size_t)MTOT * DM * 2);
  bf16* vTb   = (bf16*)alloc((size_t)MTOT * DM * 2);
  bf16* ctxb  = (bf16*)alloc((size_t)MTOT * DM * 2);

  // 1/sqrt(128) * log2(e): scores land in log2 domain for native v_exp_f32 softmax
  const float qscale = 0.08838834764831845f * 1.4426950408889634f;

  cvt_kernel<<<2048, 256, 0, stream>>>(x, xb, MTOT * DM);
  wtrans_kernel<<<dim3(DM / 64, DM / 64), 256, 0, stream>>>(wq,   wqT,   DM, DM);
  wtrans_kernel<<<dim3(DL / 64, DM / 64), 256, 0, stream>>>(wkvd, wkvdT, DM, DL);
  wtrans_kernel<<<dim3(DM / 64, DL / 64), 256, 0, stream>>>(wku,  wkuT,  DL, DM);
  wtrans_kernel<<<dim3(DM / 64, DL / 64), 256, 0, stream>>>(wvu,  wvuT,  DL, DM);
  wtrans_kernel<<<dim3(DM / 64, DM / 64), 256, 0, stream>>>(wo,   woT,   DM, DM);

  gemm_bt2<0><<<(MTOT / 128) * (DM / 128), 256, 0, stream>>>(xb,  wqT,   wqb,   qb,  DM, DM, qscale);
  gemm_bt2<0><<<(MTOT / 128) * (DL / 128), 256, 0, stream>>>(xb,  wkvdT, wkvdb, kvl, DL, DM, 1.f);
  gemm_bt2<0><<<(MTOT / 128) * (DM / 128), 256, 0, stream>>>(kvl, wkuT,  wkub,  kb,  DM, DL, 1.f);
  gemm_bt2<2><<<(MTOT / 128) * (DM / 128), 256, 0, stream>>>(kvl, wvuT,  wvub,  vTb, DM, DL, 1.f);
  mla_attn<<<BB * NH * (SS / 128), 256, 0, stream>>>(qb, kb, vTb, ctxb);
  gemm_bt2<1><<<(MTOT / 128) * (DM / 128), 256, 0, stream>>>(ctxb, woT, wob, d_out, DM, DM, 1.f);
}

// Round 13
// 230.896 us; speedup vs baseline: 1.3850x; 1.0486x over previous
//
#include <hip/hip_runtime.h>
#include <hip/hip_bf16.h>

using bf16 = __hip_bfloat16;
typedef __attribute__((ext_vector_type(8))) short short8;
typedef __attribute__((ext_vector_type(4))) float f32x4;

#define DM 2048
#define DL 512
#define NH 16
#define DKH 128
#define BB 2
#define SS 2048
#define MTOT (BB*SS)

__device__ __forceinline__ short f2b(float f) {
  bf16 h = __float2bfloat16(f);
  return *reinterpret_cast<short*>(&h);
}

__device__ __forceinline__ unsigned cvt_pk_bf16(float lo, float hi) {
  unsigned r;
  asm("v_cvt_pk_bf16_f32 %0, %1, %2" : "=v"(r) : "v"(lo), "v"(hi));
  return r;
}

__device__ __forceinline__ void gll16(const void* g, void* l) {
  __builtin_amdgcn_global_load_lds(
      (const __attribute__((address_space(1))) void*)g,
      (__attribute__((address_space(3))) void*)l, 16, 0, 0);
}

// ---------------- merged preprocessing: x->bf16 cvt + 5 weight transposes, one dispatch ----
// blocks [0,1024): grid-stride float4 cvt of x (8.4M elems).
// blocks [1024,3840): 64x64 transpose tiles; job chosen by block range (block-uniform branch).
__global__ __launch_bounds__(256) void prep_kernel(const float* __restrict__ x, bf16* __restrict__ xb,
                                                   const float* __restrict__ wq, bf16* __restrict__ wqT,
                                                   const float* __restrict__ wkvd, bf16* __restrict__ wkvdT,
                                                   const float* __restrict__ wku, bf16* __restrict__ wkuT,
                                                   const float* __restrict__ wvu, bf16* __restrict__ wvuT,
                                                   const float* __restrict__ wo, bf16* __restrict__ woT) {
  __shared__ float tile[64][65];
  int bidx = blockIdx.x;
  int t = threadIdx.x;

  if (bidx < 1024) {            // x -> bf16 (grid-stride, float4)
    int idx = (bidx * 256 + t) * 4;
    const int stride = 1024 * 256 * 4;
    short* o = reinterpret_cast<short*>(xb);
    for (int i = idx; i < MTOT * DM; i += stride) {
      float4 v = *reinterpret_cast<const float4*>(x + i);
      short4 s;
      s.x = f2b(v.x); s.y = f2b(v.y); s.z = f2b(v.z); s.w = f2b(v.w);
      *reinterpret_cast<short4*>(o + i) = s;
    }
    return;
  }

  const float* w; bf16* wt; int K, N, lb;
  if (bidx < 2048)      { w = wq;   wt = wqT;   K = DM; N = DM; lb = bidx - 1024; }
  else if (bidx < 2304) { w = wkvd; wt = wkvdT; K = DM; N = DL; lb = bidx - 2048; }
  else if (bidx < 2560) { w = wku;  wt = wkuT;  K = DL; N = DM; lb = bidx - 2304; }
  else if (bidx < 2816) { w = wvu;  wt = wvuT;  K = DL; N = DM; lb = bidx - 2560; }
  else                  { w = wo;   wt = woT;   K = DM; N = DM; lb = bidx - 2816; }
  int nbn = N >> 6;
  int tn = lb % nbn, tk = lb / nbn;
  int c = t & 63, r4 = t >> 6;
  const float* src = w + (size_t)(tk * 64) * N + tn * 64;
  #pragma unroll
  for (int rr = 0; rr < 64; rr += 4)
    tile[rr + r4][c] = src[(size_t)(rr + r4) * N + c];
  __syncthreads();
  bf16* dst = wt + (size_t)(tn * 64) * K + tk * 64;
  #pragma unroll
  for (int rr = 0; rr < 64; rr += 4)
    dst[(size_t)(rr + r4) * K + c] = __float2bfloat16(tile[c][rr + r4]);
}

// ---------------- GEMM v2 (round-7, proven): 2-phase pipelined, BK=64, dbuf, swizzled ----
template<int EPI>
__global__ __launch_bounds__(256, 2) void gemm_bt2(const bf16* __restrict__ A, const bf16* __restrict__ BT,
                                                   const float* __restrict__ bias, void* __restrict__ Cout,
                                                   int N, int K, float oscale) {
  __shared__ __align__(16) char smem[65536];
  int nbn = N >> 7;
  int nwg = gridDim.x;
  int bid = blockIdx.x;
  int cpx = nwg >> 3;                       // all grids %8==0
  bid = (bid & 7) * cpx + (bid >> 3);       // XCD-aware swizzle
  int m0 = (bid / nbn) << 7;
  int n0 = (bid % nbn) << 7;
  int t = threadIdx.x, lane = t & 63, wid = t >> 6;
  int wr = (wid >> 1) << 6, wc = (wid & 1) << 6;
  int l15 = lane & 15, l4 = lane >> 4;

  const char* asrc[4]; const char* bsrc[4]; int ldso[4];
  #pragma unroll
  for (int j = 0; j < 4; ++j) {
    int cbase = (wid * 4 + j) * 64;
    int chunk = cbase + lane;
    int off = chunk << 4;
    int row = off >> 7, col = off & 127;
    int scol = col ^ ((row & 7) << 4);
    asrc[j] = (const char*)(A + (size_t)(m0 + row) * K) + scol;
    bsrc[j] = (const char*)(BT + (size_t)(n0 + row) * K) + scol;
    ldso[j] = cbase << 4;
  }

  #pragma unroll
  for (int j = 0; j < 4; ++j) {
    gll16(asrc[j], smem + ldso[j]);
    gll16(bsrc[j], smem + 32768 + ldso[j]);
    asrc[j] += 128;
    bsrc[j] += 128;
  }
  __syncthreads();

  f32x4 acc[4][4];
  #pragma unroll
  for (int i = 0; i < 4; ++i)
    #pragma unroll
    for (int j = 0; j < 4; ++j) acc[i][j] = (f32x4){0.f, 0.f, 0.f, 0.f};

  int cur = 0;
  for (int kt = 0; kt < K; kt += 64) {
    if (kt + 64 < K) {
      char* an = smem + ((cur ^ 1) << 14);
      char* bn = smem + 32768 + ((cur ^ 1) << 14);
      #pragma unroll
      for (int j = 0; j < 4; ++j) {
        gll16(asrc[j], an + ldso[j]);
        gll16(bsrc[j], bn + ldso[j]);
      }
    }
    #pragma unroll
    for (int j = 0; j < 4; ++j) { asrc[j] += 128; bsrc[j] += 128; }

    const char* ab = smem + (cur << 14);
    const char* bb = smem + 32768 + (cur << 14);
    short8 af[4][2], bfr[4][2];
    #pragma unroll
    for (int ks = 0; ks < 2; ++ks) {
      #pragma unroll
      for (int i = 0; i < 4; ++i) {
        int row = wr + i * 16 + l15;
        int bo = row * 128 + ((ks * 64 + (l4 << 4)) ^ ((row & 7) << 4));
        af[i][ks] = *reinterpret_cast<const short8*>(ab + bo);
      }
      #pragma unroll
      for (int j2 = 0; j2 < 4; ++j2) {
        int row = wc + j2 * 16 + l15;
        int bo = row * 128 + ((ks * 64 + (l4 << 4)) ^ ((row & 7) << 4));
        bfr[j2][ks] = *reinterpret_cast<const short8*>(bb + bo);
      }
    }
    #pragma unroll
    for (int ks = 0; ks < 2; ++ks)
      #pragma unroll
      for (int i = 0; i < 4; ++i)
        #pragma unroll
        for (int j2 = 0; j2 < 4; ++j2)
          acc[i][j2] = __builtin_amdgcn_mfma_f32_16x16x32_bf16(af[i][ks], bfr[j2][ks], acc[i][j2], 0, 0, 0);

    __syncthreads();
    cur ^= 1;
  }

  int r0 = m0 + wr + (l4 << 2);
  int c0 = n0 + wc + l15;
  #pragma unroll
  for (int i = 0; i < 4; ++i) {
    #pragma unroll
    for (int j = 0; j < 4; ++j) {
      int col = c0 + j * 16;
      float bs = bias[col];
      #pragma unroll
      for (int g = 0; g < 4; ++g) {
        int row = r0 + i * 16 + g;
        float v = (acc[i][j][g] + bs) * oscale;
        if (EPI == 0) {
          ((bf16*)Cout)[(size_t)row * N + col] = __float2bfloat16(v);
        } else if (EPI == 1) {
          ((float*)Cout)[(size_t)row * N + col] = v;
        } else {
          int b = row >> 11, s = row & (SS - 1);
          int h = col >> 7, dd = col & (DKH - 1);
          ((bf16*)Cout)[((size_t)((b * NH + h) * DKH + dd)) * SS + s] = __float2bfloat16(v);
        }
      }
    }
  }
}

// ---------------- flash attention (round-7, proven): 2-phase pipelined, KVBLK=64, swapped QK^T ----
__global__ __launch_bounds__(256, 2) void mla_attn(const bf16* __restrict__ q, const bf16* __restrict__ k,
                                                   const bf16* __restrict__ vT, bf16* __restrict__ ctx) {
  __shared__ __align__(16) char smemB[81920];

  int bid = blockIdx.x;
  int x = bid & 7;
  int r = bid >> 3;
  int l = (r < 32) ? (2 * r) : (2 * (r - 32) + 1);
  int lbid = x * 64 + l;
  int bh = lbid >> 4, qt = lbid & 15;
  int b = bh >> 4, h = bh & 15;

  int t = threadIdx.x, lane = t & 63, wid = t >> 6;
  int l15 = lane & 15, l4 = lane >> 4;
  char* pScr = smemB + 65536 + (wid << 12);   // wave-private 4KB: [32 q][64 k] bf16, swizzled

  const bf16* qbase = q + ((size_t)(b * SS + qt * 128)) * DM + h * DKH;
  const bf16* kbase = k + ((size_t)(b * SS)) * DM + h * DKH;
  const bf16* vbase = vT + ((size_t)(bh * DKH)) * SS;

  #pragma unroll
  for (int j = 0; j < 8; ++j) {
    int grp = wid * 8 + j;
    int chunk = grp * 64 + lane;
    int off = chunk << 4;
    int rr = off >> 8;
    int cb = (off & 255) ^ ((rr & 7) << 4);
    char* dst = smemB + ((grp < 16) ? (grp << 10) : (32768 + ((grp - 16) << 10)));
    gll16((const char*)(qbase + (size_t)rr * DM) + cb, dst);
  }
  const char* kap[4]; const char* vap[4]; int ldsoA[4];
  #pragma unroll
  for (int j = 0; j < 4; ++j) {
    int cbase = (wid * 4 + j) * 64;
    int chunk = cbase + lane;
    int off = chunk << 4;
    int kr = off >> 8;
    int kcb = (off & 255) ^ ((kr & 7) << 4);
    gll16((const char*)(kbase + (size_t)kr * DM) + kcb, smemB + 16384 + (cbase << 4));
    int vr = off >> 7;
    int vcb = (off & 127) ^ ((vr & 7) << 4);
    gll16((const char*)(vbase + (size_t)vr * SS) + vcb, smemB + 49152 + (cbase << 4));
    kap[j] = (const char*)(kbase + (size_t)(64 + kr) * DM) + kcb;
    vap[j] = (const char*)(vbase + (size_t)vr * SS + 64) + vcb;
    ldsoA[j] = cbase << 4;
  }
  asm volatile("s_waitcnt vmcnt(8)" ::: "memory");
  __builtin_amdgcn_s_barrier();
  __builtin_amdgcn_sched_barrier(0);

  short8 qf[2][4];
  #pragma unroll
  for (int m = 0; m < 2; ++m)
    #pragma unroll
    for (int ks = 0; ks < 4; ++ks) {
      int row = wid * 32 + m * 16 + l15;
      const char* qsrc = smemB + ((row < 64) ? (row * 256) : (32768 + (row - 64) * 256));
      int kb = (ks * 64 + (l4 << 4)) ^ ((row & 7) << 4);
      qf[m][ks] = *reinterpret_cast<const short8*>(qsrc + kb);
    }

  f32x4 po[2][8];
  #pragma unroll
  for (int m = 0; m < 2; ++m)
    #pragma unroll
    for (int n = 0; n < 8; ++n) po[m][n] = (f32x4){0.f, 0.f, 0.f, 0.f};
  float mrun[2] = {-1e30f, -1e30f};
  float lrun[2] = {0.f, 0.f};

  int cur = 1;
  __syncthreads();

  for (int tt = 0; tt < 32; ++tt) {
    char* kcur = smemB + (cur << 14);
    char* vcur = smemB + 32768 + (cur << 14);

    if (tt + 1 < 32) {
      char* knxt = smemB + ((cur ^ 1) << 14);
      char* vnxt = smemB + 32768 + ((cur ^ 1) << 14);
      #pragma unroll
      for (int j = 0; j < 4; ++j) {
        gll16(kap[j], knxt + ldsoA[j]);
        gll16(vap[j], vnxt + ldsoA[j]);
      }
    }
    #pragma unroll
    for (int j = 0; j < 4; ++j) { kap[j] += 64 * DM * 2; vap[j] += 128; }

    f32x4 ps[2][4];
    #pragma unroll
    for (int m = 0; m < 2; ++m)
      #pragma unroll
      for (int n = 0; n < 4; ++n) ps[m][n] = (f32x4){0.f, 0.f, 0.f, 0.f};
    __builtin_amdgcn_s_setprio(1);
    #pragma unroll
    for (int ks = 0; ks < 4; ++ks) {
      #pragma unroll
      for (int n = 0; n < 4; ++n) {
        int row = n * 16 + l15;
        int kb = (ks * 64 + (l4 << 4)) ^ ((row & 7) << 4);
        short8 kf = *reinterpret_cast<const short8*>(kcur + row * 256 + kb);
        ps[0][n] = __builtin_amdgcn_mfma_f32_16x16x32_bf16(kf, qf[0][ks], ps[0][n], 0, 0, 0);
        ps[1][n] = __builtin_amdgcn_mfma_f32_16x16x32_bf16(kf, qf[1][ks], ps[1][n], 0, 0, 0);
      }
    }
    __builtin_amdgcn_s_setprio(0);

    float tmax[2];
    bool grow = false;
    #pragma unroll
    for (int m = 0; m < 2; ++m) {
      f32x4 vm = ps[m][0];
      #pragma unroll
      for (int n = 1; n < 4; ++n)
        #pragma unroll
        for (int g = 0; g < 4; ++g) vm[g] = fmaxf(vm[g], ps[m][n][g]);
      float v = fmaxf(fmaxf(vm[0], vm[1]), fmaxf(vm[2], vm[3]));
      v = fmaxf(v, __shfl_xor(v, 16));
      v = fmaxf(v, __shfl_xor(v, 32));
      tmax[m] = v;
      grow |= (v > mrun[m] + 11.5415603f);
    }
    if (__any(grow)) {
      float alpha[2];
      #pragma unroll
      for (int m = 0; m < 2; ++m) {
        float mnew = fmaxf(mrun[m], tmax[m]);
        alpha[m] = __builtin_amdgcn_exp2f(mrun[m] - mnew);
        mrun[m] = mnew;
        lrun[m] *= alpha[m];
      }
      #pragma unroll
      for (int m = 0; m < 2; ++m) {
        float aO[4];
        #pragma unroll
        for (int g = 0; g < 4; ++g) aO[g] = __shfl(alpha[m], (l4 << 2) + g);
        #pragma unroll
        for (int n = 0; n < 8; ++n)
          #pragma unroll
          for (int g = 0; g < 4; ++g) po[m][n][g] *= aO[g];
      }
    }

    #pragma unroll
    for (int m = 0; m < 2; ++m) {
      int qrow = m * 16 + l15;
      int swz = (qrow & 7) << 4;
      char* base = pScr + qrow * 128;
      float mr = mrun[m];
      float sn[4];
      #pragma unroll
      for (int n = 0; n < 4; ++n) {
        float p0 = __builtin_amdgcn_exp2f(ps[m][n][0] - mr);
        float p1 = __builtin_amdgcn_exp2f(ps[m][n][1] - mr);
        float p2 = __builtin_amdgcn_exp2f(ps[m][n][2] - mr);
        float p3 = __builtin_amdgcn_exp2f(ps[m][n][3] - mr);
        *reinterpret_cast<unsigned*>(base + ((n * 32 + l4 * 8 + 0) ^ swz)) = cvt_pk_bf16(p0, p1);
        *reinterpret_cast<unsigned*>(base + ((n * 32 + l4 * 8 + 4) ^ swz)) = cvt_pk_bf16(p2, p3);
        sn[n] = (p0 + p1) + (p2 + p3);
      }
      float rs = (sn[0] + sn[1]) + (sn[2] + sn[3]);
      rs += __shfl_xor(rs, 16);
      rs += __shfl_xor(rs, 32);
      lrun[m] += rs;

      __builtin_amdgcn_s_setprio(1);
      #pragma unroll
      for (int ks = 0; ks < 2; ++ks) {
        short8 pa = *reinterpret_cast<const short8*>(
            base + ((ks * 64 + (l4 << 4)) ^ swz));
        #pragma unroll
        for (int n = 0; n < 8; ++n) {
          int vrow = n * 16 + l15;
          int vb = (ks * 64 + (l4 << 4)) ^ ((vrow & 7) << 4);
          short8 vf = *reinterpret_cast<const short8*>(vcur + vrow * 128 + vb);
          po[m][n] = __builtin_amdgcn_mfma_f32_16x16x32_bf16(pa, vf, po[m][n], 0, 0, 0);
        }
      }
      __builtin_amdgcn_s_setprio(0);
    }

    __syncthreads();
    cur ^= 1;
  }

  #pragma unroll
  for (int m = 0; m < 2; ++m) {
    float invO[4];
    #pragma unroll
    for (int g = 0; g < 4; ++g) invO[g] = 1.f / __shfl(lrun[m], (l4 << 2) + g);
    #pragma unroll
    for (int g = 0; g < 4; ++g) {
      int qrow = qt * 128 + wid * 32 + m * 16 + (l4 << 2) + g;
      bf16* dst = ctx + ((size_t)(b * SS + qrow)) * DM + h * DKH;
      #pragma unroll
      for (int n = 0; n < 8; ++n)
        dst[n * 16 + l15] = __float2bfloat16(po[m][n][g] * invO[g]);
    }
  }
}

extern "C" void kernel_launch(void* const* d_in, const int* in_sizes, int n_in,
                              void* d_out, int out_size, void* d_ws, size_t ws_size,
                              hipStream_t stream) {
  (void)in_sizes; (void)n_in; (void)out_size; (void)ws_size;
  const float* x     = (const float*)d_in[0];
  const float* wq    = (const float*)d_in[2];
  const float* wqb   = (const float*)d_in[3];
  const float* wkvd  = (const float*)d_in[4];
  const float* wkvdb = (const float*)d_in[5];
  const float* wku   = (const float*)d_in[6];
  const float* wkub  = (const float*)d_in[7];
  const float* wvu   = (const float*)d_in[8];
  const float* wvub  = (const float*)d_in[9];
  const float* wo    = (const float*)d_in[10];
  const float* wob   = (const float*)d_in[11];

  char* ws = (char*)d_ws;
  size_t off = 0;
  auto alloc = [&](size_t nbytes) { void* p = ws + off; off += (nbytes + 255) & ~(size_t)255; return p; };
  bf16* xb    = (bf16*)alloc((size_t)MTOT * DM * 2);
  bf16* wqT   = (bf16*)alloc((size_t)DM * DM * 2);
  bf16* wkvdT = (bf16*)alloc((size_t)DL * DM * 2);
  bf16* wkuT  = (bf16*)alloc((size_t)DM * DL * 2);
  bf16* wvuT  = (bf16*)alloc((size_t)DM * DL * 2);
  bf16* woT   = (bf16*)alloc((size_t)DM * DM * 2);
  bf16* qb    = (bf16*)alloc((size_t)MTOT * DM * 2);
  bf16* kvl   = (bf16*)alloc((size_t)MTOT * DL * 2);
  bf16* kb    = (bf16*)alloc((size_t)MTOT * DM * 2);
  bf16* vTb   = (bf16*)alloc((size_t)MTOT * DM * 2);
  bf16* ctxb  = (bf16*)alloc((size_t)MTOT * DM * 2);

  // 1/sqrt(128) * log2(e): scores land in log2 domain for native v_exp_f32 softmax
  const float qscale = 0.08838834764831845f * 1.4426950408889634f;

  // one merged preprocessing dispatch: x cvt + all 5 weight transposes
  prep_kernel<<<3840, 256, 0, stream>>>(x, xb, wq, wqT, wkvd, wkvdT,
                                        wku, wkuT, wvu, wvuT, wo, woT);

  gemm_bt2<0><<<(MTOT / 128) * (DM / 128), 256, 0, stream>>>(xb,  wqT,   wqb,   qb,  DM, DM, qscale);
  gemm_bt2<0><<<(MTOT / 128) * (DL / 128), 256, 0, stream>>>(xb,  wkvdT, wkvdb, kvl, DL, DM, 1.f);
  gemm_bt2<0><<<(MTOT / 128) * (DM / 128), 256, 0, stream>>>(kvl, wkuT,  wkub,  kb,  DM, DL, 1.f);
  gemm_bt2<2><<<(MTOT / 128) * (DM / 128), 256, 0, stream>>>(kvl, wvuT,  wvub,  vTb, DM, DL, 1.f);
  mla_attn<<<BB * NH * (SS / 128), 256, 0, stream>>>(qb, kb, vTb, ctxb);
  gemm_bt2<1><<<(MTOT / 128) * (DM / 128), 256, 0, stream>>>(ctxb, woT, wob, d_out, DM, DM, 1.f);
}

// Round 14
// 223.884 us; speedup vs baseline: 1.4284x; 1.0313x over previous
//
#include <hip/hip_runtime.h>
#include <hip/hip_bf16.h>

using bf16 = __hip_bfloat16;
typedef __attribute__((ext_vector_type(8))) short short8;
typedef __attribute__((ext_vector_type(4))) float f32x4;
typedef __attribute__((ext_vector_type(16))) float f32x16;

#define DM 2048
#define DL 512
#define NH 16
#define DKH 128
#define BB 2
#define SS 2048
#define MTOT (BB*SS)

__device__ __forceinline__ short f2b(float f) {
  bf16 h = __float2bfloat16(f);
  return *reinterpret_cast<short*>(&h);
}

__device__ __forceinline__ unsigned cvt_pk_bf16(float lo, float hi) {
  unsigned r;
  asm("v_cvt_pk_bf16_f32 %0, %1, %2" : "=v"(r) : "v"(lo), "v"(hi));
  return r;
}

__device__ __forceinline__ void gll16(const void* g, void* l) {
  __builtin_amdgcn_global_load_lds(
      (const __attribute__((address_space(1))) void*)g,
      (__attribute__((address_space(3))) void*)l, 16, 0, 0);
}

// ---------------- merged preprocessing: x->bf16 cvt + 5 weight transposes, one dispatch ----
__global__ __launch_bounds__(256) void prep_kernel(const float* __restrict__ x, bf16* __restrict__ xb,
                                                   const float* __restrict__ wq, bf16* __restrict__ wqT,
                                                   const float* __restrict__ wkvd, bf16* __restrict__ wkvdT,
                                                   const float* __restrict__ wku, bf16* __restrict__ wkuT,
                                                   const float* __restrict__ wvu, bf16* __restrict__ wvuT,
                                                   const float* __restrict__ wo, bf16* __restrict__ woT) {
  __shared__ float tile[64][65];
  int bidx = blockIdx.x;
  int t = threadIdx.x;

  if (bidx < 1024) {            // x -> bf16 (grid-stride, float4)
    int idx = (bidx * 256 + t) * 4;
    const int stride = 1024 * 256 * 4;
    short* o = reinterpret_cast<short*>(xb);
    for (int i = idx; i < MTOT * DM; i += stride) {
      float4 v = *reinterpret_cast<const float4*>(x + i);
      short4 s;
      s.x = f2b(v.x); s.y = f2b(v.y); s.z = f2b(v.z); s.w = f2b(v.w);
      *reinterpret_cast<short4*>(o + i) = s;
    }
    return;
  }

  const float* w; bf16* wt; int K, N, lb;
  if (bidx < 2048)      { w = wq;   wt = wqT;   K = DM; N = DM; lb = bidx - 1024; }
  else if (bidx < 2304) { w = wkvd; wt = wkvdT; K = DM; N = DL; lb = bidx - 2048; }
  else if (bidx < 2560) { w = wku;  wt = wkuT;  K = DL; N = DM; lb = bidx - 2304; }
  else if (bidx < 2816) { w = wvu;  wt = wvuT;  K = DL; N = DM; lb = bidx - 2560; }
  else                  { w = wo;   wt = woT;   K = DM; N = DM; lb = bidx - 2816; }
  int nbn = N >> 6;
  int tn = lb % nbn, tk = lb / nbn;
  int c = t & 63, r4 = t >> 6;
  const float* src = w + (size_t)(tk * 64) * N + tn * 64;
  #pragma unroll
  for (int rr = 0; rr < 64; rr += 4)
    tile[rr + r4][c] = src[(size_t)(rr + r4) * N + c];
  __syncthreads();
  bf16* dst = wt + (size_t)(tn * 64) * K + tk * 64;
  #pragma unroll
  for (int rr = 0; rr < 64; rr += 4)
    dst[(size_t)(rr + r4) * K + c] = __float2bfloat16(tile[c][rr + r4]);
}

// ---------------- GEMM v2 (round-7, proven): 2-phase pipelined, BK=64, dbuf, swizzled ----
template<int EPI>
__global__ __launch_bounds__(256, 2) void gemm_bt2(const bf16* __restrict__ A, const bf16* __restrict__ BT,
                                                   const float* __restrict__ bias, void* __restrict__ Cout,
                                                   int N, int K, float oscale) {
  __shared__ __align__(16) char smem[65536];
  int nbn = N >> 7;
  int nwg = gridDim.x;
  int bid = blockIdx.x;
  int cpx = nwg >> 3;                       // all grids %8==0
  bid = (bid & 7) * cpx + (bid >> 3);       // XCD-aware swizzle
  int m0 = (bid / nbn) << 7;
  int n0 = (bid % nbn) << 7;
  int t = threadIdx.x, lane = t & 63, wid = t >> 6;
  int wr = (wid >> 1) << 6, wc = (wid & 1) << 6;
  int l15 = lane & 15, l4 = lane >> 4;

  const char* asrc[4]; const char* bsrc[4]; int ldso[4];
  #pragma unroll
  for (int j = 0; j < 4; ++j) {
    int cbase = (wid * 4 + j) * 64;
    int chunk = cbase + lane;
    int off = chunk << 4;
    int row = off >> 7, col = off & 127;
    int scol = col ^ ((row & 7) << 4);
    asrc[j] = (const char*)(A + (size_t)(m0 + row) * K) + scol;
    bsrc[j] = (const char*)(BT + (size_t)(n0 + row) * K) + scol;
    ldso[j] = cbase << 4;
  }

  #pragma unroll
  for (int j = 0; j < 4; ++j) {
    gll16(asrc[j], smem + ldso[j]);
    gll16(bsrc[j], smem + 32768 + ldso[j]);
    asrc[j] += 128;
    bsrc[j] += 128;
  }
  __syncthreads();

  f32x4 acc[4][4];
  #pragma unroll
  for (int i = 0; i < 4; ++i)
    #pragma unroll
    for (int j = 0; j < 4; ++j) acc[i][j] = (f32x4){0.f, 0.f, 0.f, 0.f};

  int cur = 0;
  for (int kt = 0; kt < K; kt += 64) {
    if (kt + 64 < K) {
      char* an = smem + ((cur ^ 1) << 14);
      char* bn = smem + 32768 + ((cur ^ 1) << 14);
      #pragma unroll
      for (int j = 0; j < 4; ++j) {
        gll16(asrc[j], an + ldso[j]);
        gll16(bsrc[j], bn + ldso[j]);
      }
    }
    #pragma unroll
    for (int j = 0; j < 4; ++j) { asrc[j] += 128; bsrc[j] += 128; }

    const char* ab = smem + (cur << 14);
    const char* bb = smem + 32768 + (cur << 14);
    short8 af[4][2], bfr[4][2];
    #pragma unroll
    for (int ks = 0; ks < 2; ++ks) {
      #pragma unroll
      for (int i = 0; i < 4; ++i) {
        int row = wr + i * 16 + l15;
        int bo = row * 128 + ((ks * 64 + (l4 << 4)) ^ ((row & 7) << 4));
        af[i][ks] = *reinterpret_cast<const short8*>(ab + bo);
      }
      #pragma unroll
      for (int j2 = 0; j2 < 4; ++j2) {
        int row = wc + j2 * 16 + l15;
        int bo = row * 128 + ((ks * 64 + (l4 << 4)) ^ ((row & 7) << 4));
        bfr[j2][ks] = *reinterpret_cast<const short8*>(bb + bo);
      }
    }
    #pragma unroll
    for (int ks = 0; ks < 2; ++ks)
      #pragma unroll
      for (int i = 0; i < 4; ++i)
        #pragma unroll
        for (int j2 = 0; j2 < 4; ++j2)
          acc[i][j2] = __builtin_amdgcn_mfma_f32_16x16x32_bf16(af[i][ks], bfr[j2][ks], acc[i][j2], 0, 0, 0);

    __syncthreads();
    cur ^= 1;
  }

  int r0 = m0 + wr + (l4 << 2);
  int c0 = n0 + wc + l15;
  #pragma unroll
  for (int i = 0; i < 4; ++i) {
    #pragma unroll
    for (int j = 0; j < 4; ++j) {
      int col = c0 + j * 16;
      float bs = bias[col];
      #pragma unroll
      for (int g = 0; g < 4; ++g) {
        int row = r0 + i * 16 + g;
        float v = (acc[i][j][g] + bs) * oscale;
        if (EPI == 0) {
          ((bf16*)Cout)[(size_t)row * N + col] = __float2bfloat16(v);
        } else if (EPI == 1) {
          ((float*)Cout)[(size_t)row * N + col] = v;
        } else {
          int b = row >> 11, s = row & (SS - 1);
          int h = col >> 7, dd = col & (DKH - 1);
          ((bf16*)Cout)[((size_t)((b * NH + h) * DKH + dd)) * SS + s] = __float2bfloat16(v);
        }
      }
    }
  }
}

// ---------------- flash attention v3: 32x32x16 MFMA, fully in-register P (no P-LDS) ----------
// Same staging/sync as round-7 (KVBLK=64 dbuf, 1 barrier/tile, XCD swizzle, defer-max,
// log2-domain exp).  Per wave: 32 q-rows (q = wid*32 + lane&31).  Swapped QK^T via
// mfma_32x32x16(K,Q) -> lane holds P^T[kv][q] for its q (kv = (r&3)+8(r>>2)+4*h5 + 32nb).
// P -> PV A-fragments built in-register: cvt_pk pairs + 8 shfl_xor(32) cross-half exchange.
// LDS = 64KB exactly (pScr eliminated).
__global__ __launch_bounds__(256, 2) void mla_attn(const bf16* __restrict__ q, const bf16* __restrict__ k,
                                                   const bf16* __restrict__ vT, bf16* __restrict__ ctx) {
  __shared__ __align__(16) char smemB[65536];

  int bid = blockIdx.x;
  int x = bid & 7;
  int r = bid >> 3;
  int l = (r < 32) ? (2 * r) : (2 * (r - 32) + 1);
  int lbid = x * 64 + l;
  int bh = lbid >> 4, qt = lbid & 15;
  int b = bh >> 4, h = bh & 15;

  int t = threadIdx.x, lane = t & 63, wid = t >> 6;
  int l31 = lane & 31, h5 = lane >> 5;

  const bf16* qbase = q + ((size_t)(b * SS + qt * 128)) * DM + h * DKH;
  const bf16* kbase = k + ((size_t)(b * SS)) * DM + h * DKH;
  const bf16* vbase = vT + ((size_t)(bh * DKH)) * SS;

  // ---- prologue: Q -> [K0|V0] regions (256B rows, swizzled); tile0 K/V -> buf1 ----
  #pragma unroll
  for (int j = 0; j < 8; ++j) {
    int grp = wid * 8 + j;
    int chunk = grp * 64 + lane;
    int off = chunk << 4;
    int rr = off >> 8;
    int cb = (off & 255) ^ ((rr & 7) << 4);
    char* dst = smemB + ((grp < 16) ? (grp << 10) : (32768 + ((grp - 16) << 10)));
    gll16((const char*)(qbase + (size_t)rr * DM) + cb, dst);
  }
  const char* kap[4]; const char* vap[4]; int ldsoA[4];
  #pragma unroll
  for (int j = 0; j < 4; ++j) {
    int cbase = (wid * 4 + j) * 64;
    int chunk = cbase + lane;
    int off = chunk << 4;
    int kr = off >> 8;
    int kcb = (off & 255) ^ ((kr & 7) << 4);
    gll16((const char*)(kbase + (size_t)kr * DM) + kcb, smemB + 16384 + (cbase << 4));
    int vr = off >> 7;
    int vcb = (off & 127) ^ ((vr & 7) << 4);
    gll16((const char*)(vbase + (size_t)vr * SS) + vcb, smemB + 49152 + (cbase << 4));
    kap[j] = (const char*)(kbase + (size_t)(64 + kr) * DM) + kcb;
    vap[j] = (const char*)(vbase + (size_t)vr * SS + 64) + vcb;
    ldsoA[j] = cbase << 4;
  }
  asm volatile("s_waitcnt vmcnt(8)" ::: "memory");
  __builtin_amdgcn_s_barrier();
  __builtin_amdgcn_sched_barrier(0);

  // q fragments: B-operand for swapped QK (col=q=l31, k-elems d=16ks+8h5+j)
  short8 qf[8];
  {
    int row = wid * 32 + l31;
    const char* qsrc = smemB + ((row < 64) ? (row * 256) : (32768 + (row - 64) * 256));
    int swz = (row & 7) << 4;
    #pragma unroll
    for (int ks = 0; ks < 8; ++ks)
      qf[ks] = *reinterpret_cast<const short8*>(qsrc + ((32 * ks + 16 * h5) ^ swz));
  }

  f32x16 po[4];
  #pragma unroll
  for (int nd = 0; nd < 4; ++nd)
    #pragma unroll
    for (int i = 0; i < 16; ++i) po[nd][i] = 0.f;
  float mrun = -1e30f, lrun = 0.f;

  int cur = 1;
  __syncthreads();   // tile0 landed; q-frag reads drained everywhere

  for (int tt = 0; tt < 32; ++tt) {
    char* kcur = smemB + (cur << 14);
    char* vcur = smemB + 32768 + (cur << 14);

    // ---- issue prefetch for tile tt+1 (stays in flight through this tile's compute) ----
    if (tt + 1 < 32) {
      char* knxt = smemB + ((cur ^ 1) << 14);
      char* vnxt = smemB + 32768 + ((cur ^ 1) << 14);
      #pragma unroll
      for (int j = 0; j < 4; ++j) {
        gll16(kap[j], knxt + ldsoA[j]);
        gll16(vap[j], vnxt + ldsoA[j]);
      }
    }
    #pragma unroll
    for (int j = 0; j < 4; ++j) { kap[j] += 64 * DM * 2; vap[j] += 128; }

    // ---- S^T = K Q^T (32x32x16): ps[nb] = P^T[kv=32nb+(r&3)+8(r>>2)+4h5][q=l31] ----
    f32x16 ps0, ps1;
    #pragma unroll
    for (int i = 0; i < 16; ++i) { ps0[i] = 0.f; ps1[i] = 0.f; }
    __builtin_amdgcn_s_setprio(1);
    {
      int swz = (l31 & 7) << 4;
      #pragma unroll
      for (int ks = 0; ks < 8; ++ks) {
        int byte = (32 * ks + 16 * h5) ^ swz;
        short8 kf0 = *reinterpret_cast<const short8*>(kcur + l31 * 256 + byte);
        short8 kf1 = *reinterpret_cast<const short8*>(kcur + (l31 + 32) * 256 + byte);
        ps0 = __builtin_amdgcn_mfma_f32_32x32x16_bf16(kf0, qf[ks], ps0, 0, 0, 0);
        ps1 = __builtin_amdgcn_mfma_f32_32x32x16_bf16(kf1, qf[ks], ps1, 0, 0, 0);
      }
    }
    __builtin_amdgcn_s_setprio(0);

    // ---- online softmax (log2 domain; one q per lane) ----
    float tv;
    {
      float a0 = ps0[0];
      #pragma unroll
      for (int i = 1; i < 16; ++i) a0 = fmaxf(a0, ps0[i]);
      float a1 = ps1[0];
      #pragma unroll
      for (int i = 1; i < 16; ++i) a1 = fmaxf(a1, ps1[i]);
      tv = fmaxf(a0, a1);
      tv = fmaxf(tv, __shfl_xor(tv, 32));
    }
    bool grow = (tv > mrun + 11.5415603f);   // 8*log2(e)
    if (__any(grow)) {
      float mnew = fmaxf(mrun, tv);
      float alpha = __builtin_amdgcn_exp2f(mrun - mnew);
      mrun = mnew;
      lrun *= alpha;
      #pragma unroll
      for (int rr = 0; rr < 16; ++rr) {
        float aR = __shfl(alpha, (rr & 3) + 8 * (rr >> 2) + 4 * h5);
        #pragma unroll
        for (int nd = 0; nd < 4; ++nd) po[nd][rr] *= aR;
      }
    }

    // ---- exp + in-register P -> A-fragment exchange ----
    {
      #pragma unroll
      for (int i = 0; i < 16; ++i) ps0[i] = __builtin_amdgcn_exp2f(ps0[i] - mrun);
      #pragma unroll
      for (int i = 0; i < 16; ++i) ps1[i] = __builtin_amdgcn_exp2f(ps1[i] - mrun);
      float rs = 0.f;
      #pragma unroll
      for (int i = 0; i < 16; ++i) rs += ps0[i] + ps1[i];
      rs += __shfl_xor(rs, 32);
      lrun += rs;

      unsigned c[16];
      #pragma unroll
      for (int i = 0; i < 8; ++i) c[i] = cvt_pk_bf16(ps0[2 * i], ps0[2 * i + 1]);
      #pragma unroll
      for (int i = 0; i < 8; ++i) c[8 + i] = cvt_pk_bf16(ps1[2 * i], ps1[2 * i + 1]);

      // cross-half exchange: send c[4ks+u] (h5=1) / c[4ks+2+u] (h5=0); receive the complement
      unsigned z8[8];
      #pragma unroll
      for (int kk = 0; kk < 8; ++kk) {
        int ks = kk >> 1, u = kk & 1;
        unsigned y = h5 ? c[4 * ks + u] : c[4 * ks + 2 + u];
        z8[kk] = (unsigned)__shfl_xor((int)y, 32);
      }

      // assemble A-frags and run PV (vf shared across nothing here; 16 MFMA)
      __builtin_amdgcn_s_setprio(1);
      int vswz = (l31 & 7) << 4;
      #pragma unroll
      for (int ks = 0; ks < 4; ++ks) {
        unsigned w0 = h5 ? z8[2 * ks]     : c[4 * ks];
        unsigned w1 = h5 ? z8[2 * ks + 1] : c[4 * ks + 1];
        unsigned w2 = h5 ? c[4 * ks + 2]  : z8[2 * ks];
        unsigned w3 = h5 ? c[4 * ks + 3]  : z8[2 * ks + 1];
        unsigned pw[4] = {w0, w1, w2, w3};
        short8 pa = *reinterpret_cast<const short8*>(pw);
        int vbyte = (32 * ks + 16 * h5) ^ vswz;
        #pragma unroll
        for (int nd = 0; nd < 4; ++nd) {
          short8 vf = *reinterpret_cast<const short8*>(vcur + (32 * nd + l31) * 128 + vbyte);
          po[nd] = __builtin_amdgcn_mfma_f32_32x32x16_bf16(pa, vf, po[nd], 0, 0, 0);
        }
      }
      __builtin_amdgcn_s_setprio(0);
    }

    __syncthreads();   // drains vmcnt(0): prefetch landed (latency covered by this tile's compute)
    cur ^= 1;
  }

  // ---- epilogue: ctx = O / l   (po[nd]: q = (r&3)+8(r>>2)+4h5, d = 32nd + l31) ----
  {
    float linv = 1.f / lrun;
    #pragma unroll
    for (int rr = 0; rr < 16; ++rr) {
      int qloc = (rr & 3) + 8 * (rr >> 2) + 4 * h5;
      float lv = __shfl(linv, qloc);
      int qrow = qt * 128 + wid * 32 + qloc;
      bf16* dst = ctx + ((size_t)(b * SS + qrow)) * DM + h * DKH + l31;
      #pragma unroll
      for (int nd = 0; nd < 4; ++nd)
        dst[32 * nd] = __float2bfloat16(po[nd][rr] * lv);
    }
  }
}

extern "C" void kernel_launch(void* const* d_in, const int* in_sizes, int n_in,
                              void* d_out, int out_size, void* d_ws, size_t ws_size,
                              hipStream_t stream) {
  (void)in_sizes; (void)n_in; (void)out_size; (void)ws_size;
  const float* x     = (const float*)d_in[0];
  const float* wq    = (const float*)d_in[2];
  const float* wqb   = (const float*)d_in[3];
  const float* wkvd  = (const float*)d_in[4];
  const float* wkvdb = (const float*)d_in[5];
  const float* wku   = (const float*)d_in[6];
  const float* wkub  = (const float*)d_in[7];
  const float* wvu   = (const float*)d_in[8];
  const float* wvub  = (const float*)d_in[9];
  const float* wo    = (const float*)d_in[10];
  const float* wob   = (const float*)d_in[11];

  char* ws = (char*)d_ws;
  size_t off = 0;
  auto alloc = [&](size_t nbytes) { void* p = ws + off; off += (nbytes + 255) & ~(size_t)255; return p; };
  bf16* xb    = (bf16*)alloc((size_t)MTOT * DM * 2);
  bf16* wqT   = (bf16*)alloc((size_t)DM * DM * 2);
  bf16* wkvdT = (bf16*)alloc((size_t)DL * DM * 2);
  bf16* wkuT  = (bf16*)alloc((size_t)DM * DL * 2);
  bf16* wvuT  = (bf16*)alloc((size_t)DM * DL * 2);
  bf16* woT   = (bf16*)alloc((size_t)DM * DM * 2);
  bf16* qb    = (bf16*)alloc((size_t)MTOT * DM * 2);
  bf16* kvl   = (bf16*)alloc((size_t)MTOT * DL * 2);
  bf16* kb    = (bf16*)alloc((size_t)MTOT * DM * 2);
  bf16* vTb   = (bf16*)alloc((size_t)MTOT * DM * 2);
  bf16* ctxb  = (bf16*)alloc((size_t)MTOT * DM * 2);

  // 1/sqrt(128) * log2(e): scores land in log2 domain for native v_exp_f32 softmax
  const float qscale = 0.08838834764831845f * 1.4426950408889634f;

  // one merged preprocessing dispatch: x cvt + all 5 weight transposes
  prep_kernel<<<3840, 256, 0, stream>>>(x, xb, wq, wqT, wkvd, wkvdT,
                                        wku, wkuT, wvu, wvuT, wo, woT);

  gemm_bt2<0><<<(MTOT / 128) * (DM / 128), 256, 0, stream>>>(xb,  wqT,   wqb,   qb,  DM, DM, qscale);
  gemm_bt2<0><<<(MTOT / 128) * (DL / 128), 256, 0, stream>>>(xb,  wkvdT, wkvdb, kvl, DL, DM, 1.f);
  gemm_bt2<0><<<(MTOT / 128) * (DM / 128), 256, 0, stream>>>(kvl, wkuT,  wkub,  kb,  DM, DL, 1.f);
  gemm_bt2<2><<<(MTOT / 128) * (DM / 128), 256, 0, stream>>>(kvl, wvuT,  wvub,  vTb, DM, DL, 1.f);
  mla_attn<<<BB * NH * (SS / 128), 256, 0, stream>>>(qb, kb, vTb, ctxb);
  gemm_bt2<1><<<(MTOT / 128) * (DM / 128), 256, 0, stream>>>(ctxb, woT, wob, d_out, DM, DM, 1.f);
}

// Round 15
// 222.808 us; speedup vs baseline: 1.4353x; 1.0048x over previous
//
#include <hip/hip_runtime.h>
#include <hip/hip_bf16.h>

using bf16 = __hip_bfloat16;
typedef __attribute__((ext_vector_type(8))) short short8;
typedef __attribute__((ext_vector_type(4))) float f32x4;
typedef __attribute__((ext_vector_type(16))) float f32x16;

#define DM 2048
#define DL 512
#define NH 16
#define DKH 128
#define BB 2
#define SS 2048
#define MTOT (BB*SS)

__device__ __forceinline__ short f2b(float f) {
  bf16 h = __float2bfloat16(f);
  return *reinterpret_cast<short*>(&h);
}

__device__ __forceinline__ unsigned cvt_pk_bf16(float lo, float hi) {
  unsigned r;
  asm("v_cvt_pk_bf16_f32 %0, %1, %2" : "=v"(r) : "v"(lo), "v"(hi));
  return r;
}

__device__ __forceinline__ void gll16(const void* g, void* l) {
  __builtin_amdgcn_global_load_lds(
      (const __attribute__((address_space(1))) void*)g,
      (__attribute__((address_space(3))) void*)l, 16, 0, 0);
}

// ---------------- merged preprocessing: x->bf16 cvt + 5 weight transposes, one dispatch ----
__global__ __launch_bounds__(256) void prep_kernel(const float* __restrict__ x, bf16* __restrict__ xb,
                                                   const float* __restrict__ wq, bf16* __restrict__ wqT,
                                                   const float* __restrict__ wkvd, bf16* __restrict__ wkvdT,
                                                   const float* __restrict__ wku, bf16* __restrict__ wkuT,
                                                   const float* __restrict__ wvu, bf16* __restrict__ wvuT,
                                                   const float* __restrict__ wo, bf16* __restrict__ woT) {
  __shared__ float tile[64][65];
  int bidx = blockIdx.x;
  int t = threadIdx.x;

  if (bidx < 1024) {            // x -> bf16 (grid-stride, float4)
    int idx = (bidx * 256 + t) * 4;
    const int stride = 1024 * 256 * 4;
    short* o = reinterpret_cast<short*>(xb);
    for (int i = idx; i < MTOT * DM; i += stride) {
      float4 v = *reinterpret_cast<const float4*>(x + i);
      short4 s;
      s.x = f2b(v.x); s.y = f2b(v.y); s.z = f2b(v.z); s.w = f2b(v.w);
      *reinterpret_cast<short4*>(o + i) = s;
    }
    return;
  }

  const float* w; bf16* wt; int K, N, lb;
  if (bidx < 2048)      { w = wq;   wt = wqT;   K = DM; N = DM; lb = bidx - 1024; }
  else if (bidx < 2304) { w = wkvd; wt = wkvdT; K = DM; N = DL; lb = bidx - 2048; }
  else if (bidx < 2560) { w = wku;  wt = wkuT;  K = DL; N = DM; lb = bidx - 2304; }
  else if (bidx < 2816) { w = wvu;  wt = wvuT;  K = DL; N = DM; lb = bidx - 2560; }
  else                  { w = wo;   wt = woT;   K = DM; N = DM; lb = bidx - 2816; }
  int nbn = N >> 6;
  int tn = lb % nbn, tk = lb / nbn;
  int c = t & 63, r4 = t >> 6;
  const float* src = w + (size_t)(tk * 64) * N + tn * 64;
  #pragma unroll
  for (int rr = 0; rr < 64; rr += 4)
    tile[rr + r4][c] = src[(size_t)(rr + r4) * N + c];
  __syncthreads();
  bf16* dst = wt + (size_t)(tn * 64) * K + tk * 64;
  #pragma unroll
  for (int rr = 0; rr < 64; rr += 4)
    dst[(size_t)(rr + r4) * K + c] = __float2bfloat16(tile[c][rr + r4]);
}

// ---------------- GEMM v2 (round-7, proven): 2-phase pipelined, BK=64, dbuf, swizzled ----
template<int EPI>
__global__ __launch_bounds__(256, 2) void gemm_bt2(const bf16* __restrict__ A, const bf16* __restrict__ BT,
                                                   const float* __restrict__ bias, void* __restrict__ Cout,
                                                   int N, int K, float oscale) {
  __shared__ __align__(16) char smem[65536];
  int nbn = N >> 7;
  int nwg = gridDim.x;
  int bid = blockIdx.x;
  int cpx = nwg >> 3;                       // all grids %8==0
  bid = (bid & 7) * cpx + (bid >> 3);       // XCD-aware swizzle
  int m0 = (bid / nbn) << 7;
  int n0 = (bid % nbn) << 7;
  int t = threadIdx.x, lane = t & 63, wid = t >> 6;
  int wr = (wid >> 1) << 6, wc = (wid & 1) << 6;
  int l15 = lane & 15, l4 = lane >> 4;

  const char* asrc[4]; const char* bsrc[4]; int ldso[4];
  #pragma unroll
  for (int j = 0; j < 4; ++j) {
    int cbase = (wid * 4 + j) * 64;
    int chunk = cbase + lane;
    int off = chunk << 4;
    int row = off >> 7, col = off & 127;
    int scol = col ^ ((row & 7) << 4);
    asrc[j] = (const char*)(A + (size_t)(m0 + row) * K) + scol;
    bsrc[j] = (const char*)(BT + (size_t)(n0 + row) * K) + scol;
    ldso[j] = cbase << 4;
  }

  #pragma unroll
  for (int j = 0; j < 4; ++j) {
    gll16(asrc[j], smem + ldso[j]);
    gll16(bsrc[j], smem + 32768 + ldso[j]);
    asrc[j] += 128;
    bsrc[j] += 128;
  }
  __syncthreads();

  f32x4 acc[4][4];
  #pragma unroll
  for (int i = 0; i < 4; ++i)
    #pragma unroll
    for (int j = 0; j < 4; ++j) acc[i][j] = (f32x4){0.f, 0.f, 0.f, 0.f};

  int cur = 0;
  for (int kt = 0; kt < K; kt += 64) {
    if (kt + 64 < K) {
      char* an = smem + ((cur ^ 1) << 14);
      char* bn = smem + 32768 + ((cur ^ 1) << 14);
      #pragma unroll
      for (int j = 0; j < 4; ++j) {
        gll16(asrc[j], an + ldso[j]);
        gll16(bsrc[j], bn + ldso[j]);
      }
    }
    #pragma unroll
    for (int j = 0; j < 4; ++j) { asrc[j] += 128; bsrc[j] += 128; }

    const char* ab = smem + (cur << 14);
    const char* bb = smem + 32768 + (cur << 14);
    short8 af[4][2], bfr[4][2];
    #pragma unroll
    for (int ks = 0; ks < 2; ++ks) {
      #pragma unroll
      for (int i = 0; i < 4; ++i) {
        int row = wr + i * 16 + l15;
        int bo = row * 128 + ((ks * 64 + (l4 << 4)) ^ ((row & 7) << 4));
        af[i][ks] = *reinterpret_cast<const short8*>(ab + bo);
      }
      #pragma unroll
      for (int j2 = 0; j2 < 4; ++j2) {
        int row = wc + j2 * 16 + l15;
        int bo = row * 128 + ((ks * 64 + (l4 << 4)) ^ ((row & 7) << 4));
        bfr[j2][ks] = *reinterpret_cast<const short8*>(bb + bo);
      }
    }
    #pragma unroll
    for (int ks = 0; ks < 2; ++ks)
      #pragma unroll
      for (int i = 0; i < 4; ++i)
        #pragma unroll
        for (int j2 = 0; j2 < 4; ++j2)
          acc[i][j2] = __builtin_amdgcn_mfma_f32_16x16x32_bf16(af[i][ks], bfr[j2][ks], acc[i][j2], 0, 0, 0);

    __syncthreads();
    cur ^= 1;
  }

  int r0 = m0 + wr + (l4 << 2);
  int c0 = n0 + wc + l15;
  #pragma unroll
  for (int i = 0; i < 4; ++i) {
    #pragma unroll
    for (int j = 0; j < 4; ++j) {
      int col = c0 + j * 16;
      float bs = bias[col];
      #pragma unroll
      for (int g = 0; g < 4; ++g) {
        int row = r0 + i * 16 + g;
        float v = (acc[i][j][g] + bs) * oscale;
        if (EPI == 0) {
          ((bf16*)Cout)[(size_t)row * N + col] = __float2bfloat16(v);
        } else if (EPI == 1) {
          ((float*)Cout)[(size_t)row * N + col] = v;
        } else {
          int b = row >> 11, s = row & (SS - 1);
          int h = col >> 7, dd = col & (DKH - 1);
          ((bf16*)Cout)[((size_t)((b * NH + h) * DKH + dd)) * SS + s] = __float2bfloat16(v);
        }
      }
    }
  }
}

// ---------------- flash attention v4: v3 + conflict-floor LDS layouts ----------------
// Same structure as v3 (32x32x16 MFMA, in-register P, KVBLK=64 dbuf, 1 barrier/tile).
// K/Q: 4-bit row swizzle ((row&15)<<4) over 256B rows -> 8-way conflicts drop to 4-way.
// V: line-packed 64x256B (line L holds d=L | d=L+64) + 4-bit swizzle -> 8-way -> 4-way.
__global__ __launch_bounds__(256, 2) void mla_attn(const bf16* __restrict__ q, const bf16* __restrict__ k,
                                                   const bf16* __restrict__ vT, bf16* __restrict__ ctx) {
  __shared__ __align__(16) char smemB[65536];

  int bid = blockIdx.x;
  int x = bid & 7;
  int r = bid >> 3;
  int l = (r < 32) ? (2 * r) : (2 * (r - 32) + 1);
  int lbid = x * 64 + l;
  int bh = lbid >> 4, qt = lbid & 15;
  int b = bh >> 4, h = bh & 15;

  int t = threadIdx.x, lane = t & 63, wid = t >> 6;
  int l31 = lane & 31, h5 = lane >> 5;

  const bf16* qbase = q + ((size_t)(b * SS + qt * 128)) * DM + h * DKH;
  const bf16* kbase = k + ((size_t)(b * SS)) * DM + h * DKH;
  const bf16* vbase = vT + ((size_t)(bh * DKH)) * SS;

  // ---- prologue: Q -> [K0|V0] regions (256B rows, 4-bit swizzle); tile0 K/V -> buf1 ----
  #pragma unroll
  for (int j = 0; j < 8; ++j) {
    int grp = wid * 8 + j;
    int chunk = grp * 64 + lane;
    int off = chunk << 4;
    int rr = off >> 8;
    int cb = (off & 255) ^ ((rr & 15) << 4);
    char* dst = smemB + ((grp < 16) ? (grp << 10) : (32768 + ((grp - 16) << 10)));
    gll16((const char*)(qbase + (size_t)rr * DM) + cb, dst);
  }
  const char* kap[4]; const char* vap[4]; int ldsoA[4];
  #pragma unroll
  for (int j = 0; j < 4; ++j) {
    int cbase = (wid * 4 + j) * 64;
    int chunk = cbase + lane;
    int off = chunk << 4;
    // K: 64 rows x 256B, 4-bit row swizzle
    int kr = off >> 8;
    int kcb = (off & 255) ^ ((kr & 15) << 4);
    gll16((const char*)(kbase + (size_t)kr * DM) + kcb, smemB + 16384 + (cbase << 4));
    // V: line-packed 64 x 256B; line L: slots 0-7 = d=L, slots 8-15 = d=L+64 (16B kv-chunks)
    int line = off >> 8;
    int sp = (off >> 4) & 15;
    int sl = sp ^ (line & 15);
    int vd = (sl < 8) ? line : (line + 64);
    int c16 = sl & 7;
    gll16((const char*)(vbase + (size_t)vd * SS) + (c16 << 4), smemB + 49152 + (cbase << 4));
    kap[j] = (const char*)(kbase + (size_t)(64 + kr) * DM) + kcb;
    vap[j] = (const char*)(vbase + (size_t)vd * SS + 64) + (c16 << 4);
    ldsoA[j] = cbase << 4;
  }
  asm volatile("s_waitcnt vmcnt(8)" ::: "memory");
  __builtin_amdgcn_s_barrier();
  __builtin_amdgcn_sched_barrier(0);

  // q fragments: B-operand for swapped QK (col=q=l31, k-elems d=16ks+8h5+j)
  short8 qf[8];
  {
    int row = wid * 32 + l31;
    const char* qsrc = smemB + ((row < 64) ? (row * 256) : (32768 + (row - 64) * 256));
    int swz = (row & 15) << 4;
    #pragma unroll
    for (int ks = 0; ks < 8; ++ks)
      qf[ks] = *reinterpret_cast<const short8*>(qsrc + ((32 * ks + 16 * h5) ^ swz));
  }

  f32x16 po[4];
  #pragma unroll
  for (int nd = 0; nd < 4; ++nd)
    #pragma unroll
    for (int i = 0; i < 16; ++i) po[nd][i] = 0.f;
  float mrun = -1e30f, lrun = 0.f;

  int cur = 1;
  __syncthreads();   // tile0 landed; q-frag reads drained everywhere

  for (int tt = 0; tt < 32; ++tt) {
    char* kcur = smemB + (cur << 14);
    char* vcur = smemB + 32768 + (cur << 14);

    // ---- issue prefetch for tile tt+1 (stays in flight through this tile's compute) ----
    if (tt + 1 < 32) {
      char* knxt = smemB + ((cur ^ 1) << 14);
      char* vnxt = smemB + 32768 + ((cur ^ 1) << 14);
      #pragma unroll
      for (int j = 0; j < 4; ++j) {
        gll16(kap[j], knxt + ldsoA[j]);
        gll16(vap[j], vnxt + ldsoA[j]);
      }
    }
    #pragma unroll
    for (int j = 0; j < 4; ++j) { kap[j] += 64 * DM * 2; vap[j] += 128; }

    // ---- S^T = K Q^T (32x32x16): ps[nb] = P^T[kv=32nb+(r&3)+8(r>>2)+4h5][q=l31] ----
    f32x16 ps0, ps1;
    #pragma unroll
    for (int i = 0; i < 16; ++i) { ps0[i] = 0.f; ps1[i] = 0.f; }
    __builtin_amdgcn_s_setprio(1);
    {
      int swz = (l31 & 15) << 4;     // (l31+32)&15 == l31&15
      #pragma unroll
      for (int ks = 0; ks < 8; ++ks) {
        int byte = (32 * ks + 16 * h5) ^ swz;
        short8 kf0 = *reinterpret_cast<const short8*>(kcur + l31 * 256 + byte);
        short8 kf1 = *reinterpret_cast<const short8*>(kcur + (l31 + 32) * 256 + byte);
        ps0 = __builtin_amdgcn_mfma_f32_32x32x16_bf16(kf0, qf[ks], ps0, 0, 0, 0);
        ps1 = __builtin_amdgcn_mfma_f32_32x32x16_bf16(kf1, qf[ks], ps1, 0, 0, 0);
      }
    }
    __builtin_amdgcn_s_setprio(0);

    // ---- online softmax (log2 domain; one q per lane) ----
    float tv;
    {
      float a0 = ps0[0];
      #pragma unroll
      for (int i = 1; i < 16; ++i) a0 = fmaxf(a0, ps0[i]);
      float a1 = ps1[0];
      #pragma unroll
      for (int i = 1; i < 16; ++i) a1 = fmaxf(a1, ps1[i]);
      tv = fmaxf(a0, a1);
      tv = fmaxf(tv, __shfl_xor(tv, 32));
    }
    bool grow = (tv > mrun + 11.5415603f);   // 8*log2(e)
    if (__any(grow)) {
      float mnew = fmaxf(mrun, tv);
      float alpha = __builtin_amdgcn_exp2f(mrun - mnew);
      mrun = mnew;
      lrun *= alpha;
      #pragma unroll
      for (int rr = 0; rr < 16; ++rr) {
        float aR = __shfl(alpha, (rr & 3) + 8 * (rr >> 2) + 4 * h5);
        #pragma unroll
        for (int nd = 0; nd < 4; ++nd) po[nd][rr] *= aR;
      }
    }

    // ---- exp + in-register P -> A-fragment exchange ----
    {
      #pragma unroll
      for (int i = 0; i < 16; ++i) ps0[i] = __builtin_amdgcn_exp2f(ps0[i] - mrun);
      #pragma unroll
      for (int i = 0; i < 16; ++i) ps1[i] = __builtin_amdgcn_exp2f(ps1[i] - mrun);
      float rs = 0.f;
      #pragma unroll
      for (int i = 0; i < 16; ++i) rs += ps0[i] + ps1[i];
      rs += __shfl_xor(rs, 32);
      lrun += rs;

      unsigned c[16];
      #pragma unroll
      for (int i = 0; i < 8; ++i) c[i] = cvt_pk_bf16(ps0[2 * i], ps0[2 * i + 1]);
      #pragma unroll
      for (int i = 0; i < 8; ++i) c[8 + i] = cvt_pk_bf16(ps1[2 * i], ps1[2 * i + 1]);

      // cross-half exchange: send c[4ks+u] (h5=1) / c[4ks+2+u] (h5=0); receive the complement
      unsigned z8[8];
      #pragma unroll
      for (int kk = 0; kk < 8; ++kk) {
        int ks = kk >> 1, u = kk & 1;
        unsigned y = h5 ? c[4 * ks + u] : c[4 * ks + 2 + u];
        z8[kk] = (unsigned)__shfl_xor((int)y, 32);
      }

      // assemble A-frags and run PV against line-packed V
      __builtin_amdgcn_s_setprio(1);
      #pragma unroll
      for (int ks = 0; ks < 4; ++ks) {
        unsigned w0 = h5 ? z8[2 * ks]     : c[4 * ks];
        unsigned w1 = h5 ? z8[2 * ks + 1] : c[4 * ks + 1];
        unsigned w2 = h5 ? c[4 * ks + 2]  : z8[2 * ks];
        unsigned w3 = h5 ? c[4 * ks + 3]  : z8[2 * ks + 1];
        unsigned pw[4] = {w0, w1, w2, w3};
        short8 pa = *reinterpret_cast<const short8*>(pw);
        #pragma unroll
        for (int nd = 0; nd < 4; ++nd) {
          int L = 32 * (nd & 1) + l31;
          int phys = (8 * (nd >> 1) + 2 * ks + h5) ^ (l31 & 15);
          short8 vf = *reinterpret_cast<const short8*>(vcur + L * 256 + (phys << 4));
          po[nd] = __builtin_amdgcn_mfma_f32_32x32x16_bf16(pa, vf, po[nd], 0, 0, 0);
        }
      }
      __builtin_amdgcn_s_setprio(0);
    }

    __syncthreads();   // drains vmcnt(0): prefetch landed (latency covered by this tile's compute)
    cur ^= 1;
  }

  // ---- epilogue: ctx = O / l   (po[nd]: q = (r&3)+8(r>>2)+4h5, d = 32nd + l31) ----
  {
    float linv = 1.f / lrun;
    #pragma unroll
    for (int rr = 0; rr < 16; ++rr) {
      int qloc = (rr & 3) + 8 * (rr >> 2) + 4 * h5;
      float lv = __shfl(linv, qloc);
      int qrow = qt * 128 + wid * 32 + qloc;
      bf16* dst = ctx + ((size_t)(b * SS + qrow)) * DM + h * DKH + l31;
      #pragma unroll
      for (int nd = 0; nd < 4; ++nd)
        dst[32 * nd] = __float2bfloat16(po[nd][rr] * lv);
    }
  }
}

extern "C" void kernel_launch(void* const* d_in, const int* in_sizes, int n_in,
                              void* d_out, int out_size, void* d_ws, size_t ws_size,
                              hipStream_t stream) {
  (void)in_sizes; (void)n_in; (void)out_size; (void)ws_size;
  const float* x     = (const float*)d_in[0];
  const float* wq    = (const float*)d_in[2];
  const float* wqb   = (const float*)d_in[3];
  const float* wkvd  = (const float*)d_in[4];
  const float* wkvdb = (const float*)d_in[5];
  const float* wku   = (const float*)d_in[6];
  const float* wkub  = (const float*)d_in[7];
  const float* wvu   = (const float*)d_in[8];
  const float* wvub  = (const float*)d_in[9];
  const float* wo    = (const float*)d_in[10];
  const float* wob   = (const float*)d_in[11];

  char* ws = (char*)d_ws;
  size_t off = 0;
  auto alloc = [&](size_t nbytes) { void* p = ws + off; off += (nbytes + 255) & ~(size_t)255; return p; };
  bf16* xb    = (bf16*)alloc((size_t)MTOT * DM * 2);
  bf16* wqT   = (bf16*)alloc((size_t)DM * DM * 2);
  bf16* wkvdT = (bf16*)alloc((size_t)DL * DM * 2);
  bf16* wkuT  = (bf16*)alloc((size_t)DM * DL * 2);
  bf16* wvuT  = (bf16*)alloc((size_t)DM * DL * 2);
  bf16* woT   = (bf16*)alloc((size_t)DM * DM * 2);
  bf16* qb    = (bf16*)alloc((size_t)MTOT * DM * 2);
  bf16* kvl   = (bf16*)alloc((size_t)MTOT * DL * 2);
  bf16* kb    = (bf16*)alloc((size_t)MTOT * DM * 2);
  bf16* vTb   = (bf16*)alloc((size_t)MTOT * DM * 2);
  bf16* ctxb  = (bf16*)alloc((size_t)MTOT * DM * 2);

  // 1/sqrt(128) * log2(e): scores land in log2 domain for native v_exp_f32 softmax
  const float qscale = 0.08838834764831845f * 1.4426950408889634f;

  // one merged preprocessing dispatch: x cvt + all 5 weight transposes
  prep_kernel<<<3840, 256, 0, stream>>>(x, xb, wq, wqT, wkvd, wkvdT,
                                        wku, wkuT, wvu, wvuT, wo, woT);

  gemm_bt2<0><<<(MTOT / 128) * (DM / 128), 256, 0, stream>>>(xb,  wqT,   wqb,   qb,  DM, DM, qscale);
  gemm_bt2<0><<<(MTOT / 128) * (DL / 128), 256, 0, stream>>>(xb,  wkvdT, wkvdb, kvl, DL, DM, 1.f);
  gemm_bt2<0><<<(MTOT / 128) * (DM / 128), 256, 0, stream>>>(kvl, wkuT,  wkub,  kb,  DM, DL, 1.f);
  gemm_bt2<2><<<(MTOT / 128) * (DM / 128), 256, 0, stream>>>(kvl, wvuT,  wvub,  vTb, DM, DL, 1.f);
  mla_attn<<<BB * NH * (SS / 128), 256, 0, stream>>>(qb, kb, vTb, ctxb);
  gemm_bt2<1><<<(MTOT / 128) * (DM / 128), 256, 0, stream>>>(ctxb, woT, wob, d_out, DM, DM, 1.f);
}